// Round 7
// baseline (742.445 us; speedup 1.0000x reference)
//
#include <hip/hip_runtime.h>
#include <cstddef>

typedef __attribute__((ext_vector_type(8))) short bf16x8;
typedef __attribute__((ext_vector_type(4))) float f32x4;
typedef __attribute__((ext_vector_type(4))) short short4v;
typedef unsigned long long u64;
typedef unsigned int u32;
typedef unsigned short u16;

#define MFMA16 __builtin_amdgcn_mfma_f32_16x16x32_bf16
static constexpr float LN_EPS = 1e-5f;
static constexpr float L2E = 1.44269504f;

__device__ __forceinline__ u16 f2bf(float f) {
    u32 u = __builtin_bit_cast(u32, f);
    return (u16)((u + 0x7FFFu + ((u >> 16) & 1u)) >> 16);
}
__device__ __forceinline__ float bf2f(u16 h) {
    u32 u = ((u32)h) << 16;
    return __builtin_bit_cast(float, u);
}

// ---------------- block-wide sum (256 threads) ----------------
__device__ __forceinline__ float block_sum256(float v) {
    __shared__ float sc[4];
    #pragma unroll
    for (int o = 32; o > 0; o >>= 1) v += __shfl_down(v, o);
    if ((threadIdx.x & 63) == 0) sc[threadIdx.x >> 6] = v;
    __syncthreads();
    v = sc[0] + sc[1] + sc[2] + sc[3];
    __syncthreads();
    return v;
}

// ---------------- prep: weights fp32 [k][n] -> bf16 Wt [mat][n][k] ----------------
__global__ __launch_bounds__(256) void prepw_kernel(
    const float* __restrict__ wq, const float* __restrict__ wk,
    const float* __restrict__ wv, const float* __restrict__ wo,
    u16* __restrict__ wt)
{
    const int mat = blockIdx.z;
    const float* W = mat == 0 ? wq : mat == 1 ? wk : mat == 2 ? wv : wo;
    const int k0 = blockIdx.x * 64, n0 = blockIdx.y * 64;
    __shared__ u16 ld[64][72];
    const int t = threadIdx.x;
    {
        const int kk = t >> 2;
        #pragma unroll
        for (int j = 0; j < 4; ++j) {
            const int nn = ((t & 3) + j * 4) * 4;
            float4 x = *(const float4*)&W[(size_t)(k0 + kk) * 512 + n0 + nn];
            ld[kk][nn + 0] = f2bf(x.x); ld[kk][nn + 1] = f2bf(x.y);
            ld[kk][nn + 2] = f2bf(x.z); ld[kk][nn + 3] = f2bf(x.w);
        }
    }
    __syncthreads();
    {
        const int n = t & 63, kc = (t >> 6) * 16;
        u16* op = wt + ((size_t)mat * 512 + n0 + n) * 512 + k0 + kc;
        #pragma unroll
        for (int j = 0; j < 4; ++j) {
            short4v v;
            v[0] = ld[kc + j*4 + 0][n]; v[1] = ld[kc + j*4 + 1][n];
            v[2] = ld[kc + j*4 + 2][n]; v[3] = ld[kc + j*4 + 3][n];
            *(short4v*)(op + j * 4) = v;
        }
    }
}

// ---------------- prep: mask int32 -> bit-packed u64 [8192 rows][32 words] ----------------
__global__ __launch_bounds__(256) void prepm_kernel(
    const int* __restrict__ mask, u64* __restrict__ bits)
{
    const int t = threadIdx.x;
    const int row = blockIdx.x * 4 + (t >> 6);
    const int wl = t & 63;
    const int* mrow = mask + (size_t)row * 2048;
    u64* brow = bits + (size_t)row * 32;
    #pragma unroll 8
    for (int it = 0; it < 32; ++it) {
        u64 b = __ballot(mrow[it * 64 + wl] != 0);
        if (wl == 0) brow[it] = b;
    }
}

// ---------------- K1: projections via MFMA. X fp32 @ Wt -> Qh/Kh/Vh bf16 [bh][s][64]
__global__ __launch_bounds__(256) void proj_kernel(
    const float* __restrict__ qin, const float* __restrict__ kin, const float* __restrict__ vin,
    const u16* __restrict__ wt,
    u16* __restrict__ Qh, u16* __restrict__ Kh, u16* __restrict__ Vh)
{
    const int z = blockIdx.z;
    const float* X = z == 0 ? qin : (z == 1 ? kin : vin);
    const u16* W = wt + (size_t)z * 512 * 512;
    u16* O = z == 0 ? Qh : (z == 1 ? Kh : Vh);
    const int m0 = blockIdx.x * 64;
    const int h = blockIdx.y;
    const int t = threadIdx.x, l = t & 63, w = t >> 6;
    const int q = l & 15, G = l >> 4;
    const int wr = w >> 1, wc = w & 1;

    f32x4 acc[2][2] = {};
    for (int k0 = 0; k0 < 512; k0 += 32) {
        bf16x8 af[2], bfr[2];
        #pragma unroll
        for (int mi = 0; mi < 2; ++mi) {
            const float* xp = X + (size_t)(m0 + wr*32 + mi*16 + q) * 512 + k0 + G*8;
            float4 x0 = *(const float4*)xp;
            float4 x1 = *(const float4*)(xp + 4);
            bf16x8 a;
            a[0] = f2bf(x0.x); a[1] = f2bf(x0.y); a[2] = f2bf(x0.z); a[3] = f2bf(x0.w);
            a[4] = f2bf(x1.x); a[5] = f2bf(x1.y); a[6] = f2bf(x1.z); a[7] = f2bf(x1.w);
            af[mi] = a;
        }
        #pragma unroll
        for (int tn = 0; tn < 2; ++tn)
            bfr[tn] = *(const bf16x8*)(W + (size_t)(h*64 + wc*32 + tn*16 + q) * 512 + k0 + G*8);
        #pragma unroll
        for (int mi = 0; mi < 2; ++mi)
            #pragma unroll
            for (int tn = 0; tn < 2; ++tn)
                acc[mi][tn] = MFMA16(af[mi], bfr[tn], acc[mi][tn], 0, 0, 0);
    }
    const float scv = (z == 0) ? 0.125f : 1.0f;   // fold 1/sqrt(64) into Q (exact pow2)
    #pragma unroll
    for (int mi = 0; mi < 2; ++mi)
        #pragma unroll
        for (int tn = 0; tn < 2; ++tn)
            #pragma unroll
            for (int r = 0; r < 4; ++r) {
                const int m = m0 + wr*32 + mi*16 + G*4 + r;
                const int b = m >> 11, s = m & 2047;
                const int d = wc*32 + tn*16 + q;
                O[(((size_t)(b*8 + h) << 11) + s) * 64 + d] = f2bf(acc[mi][tn][r] * scv);
            }
}

// ---------------- V transpose: Vh [bh][s][64] -> Vt [bh][64][2048] ----------------
__global__ __launch_bounds__(256) void vt_kernel(
    const u16* __restrict__ Vh, u16* __restrict__ Vt)
{
    const int bh = blockIdx.y, s0 = blockIdx.x * 64;
    __shared__ u16 ld[64][72];
    const int t = threadIdx.x;
    {
        const int s = t >> 2, dg = (t & 3) * 16;
        const u16* vp = Vh + ((((size_t)bh << 11) + s0 + s) * 64) + dg;
        *(bf16x8*)&ld[s][dg]     = *(const bf16x8*)vp;
        *(bf16x8*)&ld[s][dg + 8] = *(const bf16x8*)(vp + 8);
    }
    __syncthreads();
    {
        const int d = t & 63, sc = (t >> 6) * 16;
        u16* op = Vt + (((size_t)bh << 6) + d) * 2048 + s0 + sc;
        #pragma unroll
        for (int j = 0; j < 4; ++j) {
            short4v v;
            v[0] = ld[sc + j*4 + 0][d]; v[1] = ld[sc + j*4 + 1][d];
            v[2] = ld[sc + j*4 + 2][d]; v[3] = ld[sc + j*4 + 3][d];
            *(short4v*)(op + j * 4) = v;
        }
    }
}

// ---------------- S: E = exp(QK^T) masked, row-major bf16 -> ws; partial row sums ----------------
// grid (nt=8, qt=32, bh=32). K-fragments double-buffered across subs; E stored nontemporal.
__global__ __launch_bounds__(256) void score_kernel(
    const u16* __restrict__ Qh, const u16* __restrict__ Kh,
    const u64* __restrict__ bits, u16* __restrict__ E, float* __restrict__ psum)
{
    const int nt = blockIdx.x, qt = blockIdx.y, bh = blockIdx.z;
    const int b = bh >> 3;
    const int m0 = qt * 64;
    const int t = threadIdx.x, l = t & 63, w = t >> 6;
    const int q = l & 15, G = l >> 4;
    const int qrow = m0 + w*16 + q;
    const size_t qbase = (((size_t)bh << 11) + qrow) * 64;
    bf16x8 qf0 = *(const bf16x8*)(Qh + qbase + G*8);
    bf16x8 qf1 = *(const bf16x8*)(Qh + qbase + 32 + G*8);
    const u64* brow = bits + (((size_t)b << 11) + qrow) * 32;
    u16* erow = E + ((((size_t)bh << 11) + qrow) << 11);
    float rs = 0.f;

    bf16x8 kc[8], kn[8];
    {
        const int n0 = nt*256;
        #pragma unroll
        for (int mt = 0; mt < 4; ++mt) {
            const size_t kb = ((((size_t)bh << 11) + n0 + mt*16 + q) * 64) + G*8;
            kc[mt*2]   = *(const bf16x8*)(Kh + kb);
            kc[mt*2+1] = *(const bf16x8*)(Kh + kb + 32);
        }
    }
    #pragma unroll
    for (int sub = 0; sub < 4; ++sub) {
        const int n0 = nt*256 + sub*64;
        if (sub < 3) {
            const int n1 = n0 + 64;
            #pragma unroll
            for (int mt = 0; mt < 4; ++mt) {
                const size_t kb = ((((size_t)bh << 11) + n1 + mt*16 + q) * 64) + G*8;
                kn[mt*2]   = *(const bf16x8*)(Kh + kb);
                kn[mt*2+1] = *(const bf16x8*)(Kh + kb + 32);
            }
        }
        f32x4 acc[4] = {};
        #pragma unroll
        for (int mt = 0; mt < 4; ++mt) {
            acc[mt] = MFMA16(kc[mt*2],   qf0, acc[mt], 0, 0, 0);
            acc[mt] = MFMA16(kc[mt*2+1], qf1, acc[mt], 0, 0, 0);
        }
        const u64 mw = brow[n0 >> 6];
        #pragma unroll
        for (int mt = 0; mt < 4; ++mt) {
            short4v sv;
            #pragma unroll
            for (int r = 0; r < 4; ++r) {
                const int c = mt*16 + G*4 + r;
                const float e = ((mw >> c) & 1) ? 0.f : exp2f(acc[mt][r] * L2E);
                rs += e;
                sv[r] = (short)f2bf(e);
            }
            __builtin_nontemporal_store(sv, (short4v*)(erow + n0 + mt*16 + G*4));
        }
        #pragma unroll
        for (int i = 0; i < 8; ++i) kc[i] = kn[i];
    }
    rs += __shfl_xor(rs, 16);
    rs += __shfl_xor(rs, 32);
    if (G == 0) psum[(((((size_t)bh << 11) + qrow)) << 3) + nt] = rs;
}

// ---------------- R: invs = 1/sum(psum[row][0..7]) ----------------
__global__ __launch_bounds__(256) void invs_kernel(
    const float* __restrict__ psum, float* __restrict__ invs)
{
    const int i = blockIdx.x * 256 + threadIdx.x;   // 0..65535
    float4 a = *(const float4*)&psum[(size_t)i * 8];
    float4 b = *(const float4*)&psum[(size_t)i * 8 + 4];
    invs[i] = 1.0f / (a.x + a.y + a.z + a.w + b.x + b.y + b.z + b.w);
}

// ---------------- PV: read E, write normalized attn (nontemporal), accumulate heads ----------------
// grid (qt=32, bh=32). E and V register double-buffered across key tiles.
__global__ __launch_bounds__(256) void pv_kernel(
    const u16* __restrict__ E, const u16* __restrict__ Vt, const float* __restrict__ invs,
    float* __restrict__ attn, u16* __restrict__ heads)
{
    const int qt = blockIdx.x, bh = blockIdx.y;
    const int b = bh >> 3, h = bh & 7;
    const int m0 = qt * 64;
    const int t = threadIdx.x, l = t & 63, w = t >> 6;
    const int q = l & 15, G = l >> 4;
    const int qrow = m0 + w*16 + q;
    const u16* erow = E + ((((size_t)bh << 11) + qrow) << 11);
    const float inv = invs[((size_t)bh << 11) + qrow];
    float* arow = attn + ((((size_t)bh << 11) + qrow) << 11);
    f32x4 pacc[4] = {};

    bf16x8 ec0, ec1, en0, en1;
    bf16x8 vc[8], vn[8];
    {
        ec0 = *(const bf16x8*)(erow + G*8);
        ec1 = *(const bf16x8*)(erow + 32 + G*8);
        #pragma unroll
        for (int dmt = 0; dmt < 4; ++dmt) {
            const size_t vb = ((((size_t)bh << 6) + dmt*16 + q) * 2048) + G*8;
            vc[dmt*2]   = *(const bf16x8*)(Vt + vb);
            vc[dmt*2+1] = *(const bf16x8*)(Vt + vb + 32);
        }
    }
    for (int n0 = 0; n0 < 2048; n0 += 64) {
        if (n0 < 2048 - 64) {
            const int n1 = n0 + 64;
            en0 = *(const bf16x8*)(erow + n1 + G*8);
            en1 = *(const bf16x8*)(erow + n1 + 32 + G*8);
            #pragma unroll
            for (int dmt = 0; dmt < 4; ++dmt) {
                const size_t vb = ((((size_t)bh << 6) + dmt*16 + q) * 2048) + n1 + G*8;
                vn[dmt*2]   = *(const bf16x8*)(Vt + vb);
                vn[dmt*2+1] = *(const bf16x8*)(Vt + vb + 32);
            }
        }
        // normalized attn write (f32, nontemporal), 4x 16B per lane over 64 keys/row
        f32x4 f0, f1, f2, f3;
        #pragma unroll
        for (int j = 0; j < 4; ++j) {
            f0[j] = bf2f((u16)ec0[j])     * inv;
            f1[j] = bf2f((u16)ec0[j + 4]) * inv;
            f2[j] = bf2f((u16)ec1[j])     * inv;
            f3[j] = bf2f((u16)ec1[j + 4]) * inv;
        }
        __builtin_nontemporal_store(f0, (f32x4*)(arow + n0 + G*8));
        __builtin_nontemporal_store(f1, (f32x4*)(arow + n0 + G*8 + 4));
        __builtin_nontemporal_store(f2, (f32x4*)(arow + n0 + 32 + G*8));
        __builtin_nontemporal_store(f3, (f32x4*)(arow + n0 + 32 + G*8 + 4));
        #pragma unroll
        for (int dmt = 0; dmt < 4; ++dmt) {
            pacc[dmt] = MFMA16(vc[dmt*2],   ec0, pacc[dmt], 0, 0, 0);
            pacc[dmt] = MFMA16(vc[dmt*2+1], ec1, pacc[dmt], 0, 0, 0);
        }
        ec0 = en0; ec1 = en1;
        #pragma unroll
        for (int i = 0; i < 8; ++i) vc[i] = vn[i];
    }
    #pragma unroll
    for (int dmt = 0; dmt < 4; ++dmt) {
        short4v sv;
        #pragma unroll
        for (int r = 0; r < 4; ++r) sv[r] = (short)f2bf(pacc[dmt][r] * inv);
        *(short4v*)&heads[(((size_t)b << 11) + qrow) * 512 + h*64 + dmt*16 + G*4] = sv;
    }
}

// ---------------- K4: out = heads(bf16) @ wo + q residual ----------------
__global__ __launch_bounds__(256) void outgemm_kernel(
    const u16* __restrict__ heads, const u16* __restrict__ wt,
    const float* __restrict__ qin, float* __restrict__ out)
{
    const int m0 = blockIdx.x * 64, n0b = blockIdx.y * 64;
    const int t = threadIdx.x, l = t & 63, w = t >> 6;
    const int q = l & 15, G = l >> 4;
    const int wr = w >> 1, wc = w & 1;
    const u16* W = wt + (size_t)3 * 512 * 512;
    f32x4 acc[2][2] = {};
    for (int k0 = 0; k0 < 512; k0 += 32) {
        bf16x8 af[2], bfr[2];
        #pragma unroll
        for (int mi = 0; mi < 2; ++mi)
            af[mi] = *(const bf16x8*)(heads + (size_t)(m0 + wr*32 + mi*16 + q) * 512 + k0 + G*8);
        #pragma unroll
        for (int tn = 0; tn < 2; ++tn)
            bfr[tn] = *(const bf16x8*)(W + (size_t)(n0b + wc*32 + tn*16 + q) * 512 + k0 + G*8);
        #pragma unroll
        for (int mi = 0; mi < 2; ++mi)
            #pragma unroll
            for (int tn = 0; tn < 2; ++tn)
                acc[mi][tn] = MFMA16(af[mi], bfr[tn], acc[mi][tn], 0, 0, 0);
    }
    #pragma unroll
    for (int mi = 0; mi < 2; ++mi)
        #pragma unroll
        for (int r = 0; r < 4; ++r) {
            const int m = m0 + wr*32 + mi*16 + G*4 + r;
            #pragma unroll
            for (int tn = 0; tn < 2; ++tn) {
                const int n = n0b + wc*32 + tn*16 + q;
                out[(size_t)m * 512 + n] = acc[mi][tn][r] + qin[(size_t)m * 512 + n];
            }
        }
}

// ---------------- K5: in-place row LayerNorm ----------------
__global__ __launch_bounds__(256) void ln_kernel(
    float* __restrict__ out, const float* __restrict__ g, const float* __restrict__ be)
{
    const int m = blockIdx.x;
    float* row = out + (size_t)m * 512;
    const int t = threadIdx.x;
    float2 v = ((const float2*)row)[t];
    float s  = block_sum256(v.x + v.y);
    float s2 = block_sum256(v.x * v.x + v.y * v.y);
    const float mu  = s * (1.0f / 512.0f);
    const float var = s2 * (1.0f / 512.0f) - mu * mu;
    const float inv = rsqrtf(var + LN_EPS);
    float2 gg = ((const float2*)g)[t];
    float2 bb = ((const float2*)be)[t];
    float2 r;
    r.x = (v.x - mu) * inv * gg.x + bb.x;
    r.y = (v.y - mu) * inv * gg.y + bb.y;
    ((float2*)row)[t] = r;
}

// ---------------- launch ----------------
extern "C" void kernel_launch(void* const* d_in, const int* in_sizes, int n_in,
                              void* d_out, int out_size, void* d_ws, size_t ws_size,
                              hipStream_t stream) {
    const float* q   = (const float*)d_in[0];
    const float* k   = (const float*)d_in[1];
    const float* v   = (const float*)d_in[2];
    const float* wq  = (const float*)d_in[3];
    const float* wk  = (const float*)d_in[4];
    const float* wv  = (const float*)d_in[5];
    const float* wo  = (const float*)d_in[6];
    const float* g   = (const float*)d_in[7];
    const float* be  = (const float*)d_in[8];
    const int*   msk = (const int*)d_in[9];

    float* out  = (float*)d_out;
    float* attn = out + (size_t)4 * 2048 * 512;

    const size_t nQKV = (size_t)32 * 2048 * 64;          // 4M u16 per tensor
    u16* Qh    = (u16*)d_ws;
    u16* Kh    = Qh + nQKV;
    u16* Vh    = Kh + nQKV;
    u16* Vt    = Vh + nQKV;
    u16* heads = Vt + nQKV;
    u16* wt    = heads + (size_t)8192 * 512;
    u64* bits  = (u64*)(wt + (size_t)4 * 512 * 512);
    float* psum = (float*)(bits + (size_t)8192 * 32);    // 65536*8 f32 = 2MB
    float* invs = psum + (size_t)65536 * 8;              // 65536 f32
    u16* E      = (u16*)(invs + 65536);                  // 32*2048*2048 bf16 = 268MB

    prepw_kernel  <<<dim3(8, 8, 4),    256, 0, stream>>>(wq, wk, wv, wo, wt);
    prepm_kernel  <<<dim3(2048),       256, 0, stream>>>(msk, bits);
    proj_kernel   <<<dim3(128, 8, 3),  256, 0, stream>>>(q, k, v, wt, Qh, Kh, Vh);
    vt_kernel     <<<dim3(32, 32),     256, 0, stream>>>(Vh, Vt);
    score_kernel  <<<dim3(8, 32, 32),  256, 0, stream>>>(Qh, Kh, bits, E, psum);
    invs_kernel   <<<dim3(256),        256, 0, stream>>>(psum, invs);
    pv_kernel     <<<dim3(32, 32),     256, 0, stream>>>(E, Vt, invs, attn, heads);
    outgemm_kernel<<<dim3(128, 8),     256, 0, stream>>>(heads, wt, q, out);
    ln_kernel     <<<dim3(8192),       256, 0, stream>>>(out, g, be);
}

// Round 8
// 653.151 us; speedup vs baseline: 1.1367x; 1.1367x over previous
//
#include <hip/hip_runtime.h>
#include <cstddef>

typedef __attribute__((ext_vector_type(8))) short bf16x8;
typedef __attribute__((ext_vector_type(4))) float f32x4;
typedef __attribute__((ext_vector_type(4))) short short4v;
typedef unsigned long long u64;
typedef unsigned int u32;
typedef unsigned short u16;

#define MFMA16 __builtin_amdgcn_mfma_f32_16x16x32_bf16
static constexpr float LN_EPS = 1e-5f;
static constexpr float L2E = 1.44269504f;

__device__ __forceinline__ u16 f2bf(float f) {
    u32 u = __builtin_bit_cast(u32, f);
    return (u16)((u + 0x7FFFu + ((u >> 16) & 1u)) >> 16);
}
__device__ __forceinline__ float bf2f(u16 h) {
    u32 u = ((u32)h) << 16;
    return __builtin_bit_cast(float, u);
}

// ---------------- block-wide sum (256 threads) ----------------
__device__ __forceinline__ float block_sum256(float v) {
    __shared__ float sc[4];
    #pragma unroll
    for (int o = 32; o > 0; o >>= 1) v += __shfl_down(v, o);
    if ((threadIdx.x & 63) == 0) sc[threadIdx.x >> 6] = v;
    __syncthreads();
    v = sc[0] + sc[1] + sc[2] + sc[3];
    __syncthreads();
    return v;
}

// ---------------- prep: weights fp32 [k][n] -> bf16 Wt [mat][n][k] ----------------
__global__ __launch_bounds__(256) void prepw_kernel(
    const float* __restrict__ wq, const float* __restrict__ wk,
    const float* __restrict__ wv, const float* __restrict__ wo,
    u16* __restrict__ wt)
{
    const int mat = blockIdx.z;
    const float* W = mat == 0 ? wq : mat == 1 ? wk : mat == 2 ? wv : wo;
    const int k0 = blockIdx.x * 64, n0 = blockIdx.y * 64;
    __shared__ u16 ld[64][72];
    const int t = threadIdx.x;
    {
        const int kk = t >> 2;
        #pragma unroll
        for (int j = 0; j < 4; ++j) {
            const int nn = ((t & 3) + j * 4) * 4;
            float4 x = *(const float4*)&W[(size_t)(k0 + kk) * 512 + n0 + nn];
            ld[kk][nn + 0] = f2bf(x.x); ld[kk][nn + 1] = f2bf(x.y);
            ld[kk][nn + 2] = f2bf(x.z); ld[kk][nn + 3] = f2bf(x.w);
        }
    }
    __syncthreads();
    {
        const int n = t & 63, kc = (t >> 6) * 16;
        u16* op = wt + ((size_t)mat * 512 + n0 + n) * 512 + k0 + kc;
        #pragma unroll
        for (int j = 0; j < 4; ++j) {
            short4v v;
            v[0] = ld[kc + j*4 + 0][n]; v[1] = ld[kc + j*4 + 1][n];
            v[2] = ld[kc + j*4 + 2][n]; v[3] = ld[kc + j*4 + 3][n];
            *(short4v*)(op + j * 4) = v;
        }
    }
}

// ---------------- prep: mask int32 -> bit-packed u64 [8192 rows][32 words] ----------------
__global__ __launch_bounds__(256) void prepm_kernel(
    const int* __restrict__ mask, u64* __restrict__ bits)
{
    const int t = threadIdx.x;
    const int row = blockIdx.x * 4 + (t >> 6);
    const int wl = t & 63;
    const int* mrow = mask + (size_t)row * 2048;
    u64* brow = bits + (size_t)row * 32;
    #pragma unroll 8
    for (int it = 0; it < 32; ++it) {
        u64 b = __ballot(mrow[it * 64 + wl] != 0);
        if (wl == 0) brow[it] = b;
    }
}

// ---------------- K1: projections via MFMA. X fp32 @ Wt -> Qh/Kh/Vh bf16 [bh][s][64]
__global__ __launch_bounds__(256) void proj_kernel(
    const float* __restrict__ qin, const float* __restrict__ kin, const float* __restrict__ vin,
    const u16* __restrict__ wt,
    u16* __restrict__ Qh, u16* __restrict__ Kh, u16* __restrict__ Vh)
{
    const int z = blockIdx.z;
    const float* X = z == 0 ? qin : (z == 1 ? kin : vin);
    const u16* W = wt + (size_t)z * 512 * 512;
    u16* O = z == 0 ? Qh : (z == 1 ? Kh : Vh);
    const int m0 = blockIdx.x * 64;
    const int h = blockIdx.y;
    const int t = threadIdx.x, l = t & 63, w = t >> 6;
    const int q = l & 15, G = l >> 4;
    const int wr = w >> 1, wc = w & 1;

    f32x4 acc[2][2] = {};
    for (int k0 = 0; k0 < 512; k0 += 32) {
        bf16x8 af[2], bfr[2];
        #pragma unroll
        for (int mi = 0; mi < 2; ++mi) {
            const float* xp = X + (size_t)(m0 + wr*32 + mi*16 + q) * 512 + k0 + G*8;
            float4 x0 = *(const float4*)xp;
            float4 x1 = *(const float4*)(xp + 4);
            bf16x8 a;
            a[0] = f2bf(x0.x); a[1] = f2bf(x0.y); a[2] = f2bf(x0.z); a[3] = f2bf(x0.w);
            a[4] = f2bf(x1.x); a[5] = f2bf(x1.y); a[6] = f2bf(x1.z); a[7] = f2bf(x1.w);
            af[mi] = a;
        }
        #pragma unroll
        for (int tn = 0; tn < 2; ++tn)
            bfr[tn] = *(const bf16x8*)(W + (size_t)(h*64 + wc*32 + tn*16 + q) * 512 + k0 + G*8);
        #pragma unroll
        for (int mi = 0; mi < 2; ++mi)
            #pragma unroll
            for (int tn = 0; tn < 2; ++tn)
                acc[mi][tn] = MFMA16(af[mi], bfr[tn], acc[mi][tn], 0, 0, 0);
    }
    const float scv = (z == 0) ? 0.125f : 1.0f;   // fold 1/sqrt(64) into Q (exact pow2)
    #pragma unroll
    for (int mi = 0; mi < 2; ++mi)
        #pragma unroll
        for (int tn = 0; tn < 2; ++tn)
            #pragma unroll
            for (int r = 0; r < 4; ++r) {
                const int m = m0 + wr*32 + mi*16 + G*4 + r;
                const int b = m >> 11, s = m & 2047;
                const int d = wc*32 + tn*16 + q;
                O[(((size_t)(b*8 + h) << 11) + s) * 64 + d] = f2bf(acc[mi][tn][r] * scv);
            }
}

// ---------------- V transpose: Vh [bh][s][64] -> Vt [bh][64][2048] ----------------
__global__ __launch_bounds__(256) void vt_kernel(
    const u16* __restrict__ Vh, u16* __restrict__ Vt)
{
    const int bh = blockIdx.y, s0 = blockIdx.x * 64;
    __shared__ u16 ld[64][72];
    const int t = threadIdx.x;
    {
        const int s = t >> 2, dg = (t & 3) * 16;
        const u16* vp = Vh + ((((size_t)bh << 11) + s0 + s) * 64) + dg;
        *(bf16x8*)&ld[s][dg]     = *(const bf16x8*)vp;
        *(bf16x8*)&ld[s][dg + 8] = *(const bf16x8*)(vp + 8);
    }
    __syncthreads();
    {
        const int d = t & 63, sc = (t >> 6) * 16;
        u16* op = Vt + (((size_t)bh << 6) + d) * 2048 + s0 + sc;
        #pragma unroll
        for (int j = 0; j < 4; ++j) {
            short4v v;
            v[0] = ld[sc + j*4 + 0][d]; v[1] = ld[sc + j*4 + 1][d];
            v[2] = ld[sc + j*4 + 2][d]; v[3] = ld[sc + j*4 + 3][d];
            *(short4v*)(op + j * 4) = v;
        }
    }
}

// ---------------- fused attn: QK^T -> exp -> {rowsum, E-tile store, PV} single pass ----------------
// grid 1024 (XCD-swizzled -> qt 0..31, bh 0..31). Et layout [bh][qt][kt][64][64] bf16.
__global__ __launch_bounds__(256) void attnpv_kernel(
    const u16* __restrict__ Qh, const u16* __restrict__ Kh, const u16* __restrict__ Vt,
    const u64* __restrict__ bits,
    u16* __restrict__ Et, float* __restrict__ invs, u16* __restrict__ heads)
{
    const int j   = blockIdx.x;
    const int lid = (j & 7) * 128 + (j >> 3);     // XCD-contiguous bh ranges
    const int qt = lid & 31, bh = lid >> 5;
    const int b = bh >> 3, h = bh & 7;
    const int m0 = qt * 64;
    const int t = threadIdx.x, l = t & 63, w = t >> 6;
    const int q = l & 15, G = l >> 4;
    const int qrow = m0 + w*16 + q;
    __shared__ u16 alds[4][1024];          // per-wave 16x64 bf16 E tile, XOR-swizzled
    u16* my = alds[w];
    const size_t qbase = (((size_t)bh << 11) + qrow) * 64;
    bf16x8 qf0 = *(const bf16x8*)(Qh + qbase + G*8);
    bf16x8 qf1 = *(const bf16x8*)(Qh + qbase + 32 + G*8);
    const u64* brow = bits + (((size_t)b << 11) + qrow) * 32;
    const int swz = (q & 7) << 3;
    // E-tile store mapping: lane covers sub-row sr, 32B starting at col c16
    const int sr  = l >> 2;
    const int c16 = (l & 3) * 16;
    const int ssw = (sr & 7) << 3;
    u16* etq = Et + (((size_t)bh * 32 + qt) << 17);   // *32*4096
    float rs = 0.f;
    f32x4 pacc[4] = {};

    for (int n0 = 0; n0 < 2048; n0 += 64) {
        const int kt = n0 >> 6;
        f32x4 acc[4] = {};
        #pragma unroll
        for (int mt = 0; mt < 4; ++mt) {
            const size_t kb = ((((size_t)bh << 11) + n0 + mt*16 + q) * 64) + G*8;
            bf16x8 k0 = *(const bf16x8*)(Kh + kb);
            bf16x8 k1 = *(const bf16x8*)(Kh + kb + 32);
            acc[mt] = MFMA16(k0, qf0, acc[mt], 0, 0, 0);
            acc[mt] = MFMA16(k1, qf1, acc[mt], 0, 0, 0);
        }
        const u64 mw = brow[kt];
        #pragma unroll
        for (int mt = 0; mt < 4; ++mt) {
            short4v sv;
            #pragma unroll
            for (int r = 0; r < 4; ++r) {
                const int c = mt*16 + G*4 + r;
                const float e = ((mw >> c) & 1) ? 0.f : exp2f(acc[mt][r] * L2E);
                rs += e;
                sv[r] = (short)f2bf(e);
            }
            *(short4v*)&my[(q*64 + mt*16 + G*4) ^ swz] = sv;
        }
        // PV fragments (per-row contiguous keys)
        bf16x8 an0 = *(const bf16x8*)&my[(q*64 +  0 + G*8) ^ swz];
        bf16x8 an1 = *(const bf16x8*)&my[(q*64 + 32 + G*8) ^ swz];
        // E tile store: wave writes its 16x64 tile as contiguous 2KB
        {
            u16* et = etq + (kt << 12) + (w * 16) * 64;
            bf16x8 e0 = *(const bf16x8*)&my[sr*64 + ((c16 + 0) ^ ssw)];
            bf16x8 e1 = *(const bf16x8*)&my[sr*64 + ((c16 + 8) ^ ssw)];
            *(bf16x8*)(et + sr*64 + c16)     = e0;
            *(bf16x8*)(et + sr*64 + c16 + 8) = e1;
        }
        #pragma unroll
        for (int dmt = 0; dmt < 4; ++dmt) {
            const size_t vb = ((((size_t)bh << 6) + dmt*16 + q) * 2048) + n0 + G*8;
            bf16x8 v0 = *(const bf16x8*)(Vt + vb);
            bf16x8 v1 = *(const bf16x8*)(Vt + vb + 32);
            pacc[dmt] = MFMA16(v0, an0, pacc[dmt], 0, 0, 0);
            pacc[dmt] = MFMA16(v1, an1, pacc[dmt], 0, 0, 0);
        }
    }
    // row sums -> inv (reduce over the 4 G-groups holding the same q-row)
    rs += __shfl_xor(rs, 16);
    rs += __shfl_xor(rs, 32);
    const float inv = 1.0f / rs;
    if (G == 0) invs[((size_t)bh << 11) + qrow] = inv;
    #pragma unroll
    for (int dmt = 0; dmt < 4; ++dmt) {
        short4v sv;
        #pragma unroll
        for (int r = 0; r < 4; ++r) sv[r] = (short)f2bf(pacc[dmt][r] * inv);
        *(short4v*)&heads[(((size_t)b << 11) + qrow) * 512 + h*64 + dmt*16 + G*4] = sv;
    }
}

// ---------------- expand: attn[f32 row-major] = Et[tiled bf16] * invs ----------------
// grid (128 row-chunks, 32 bh). Pure streaming: coalesced 16B reads, 8KB-row writes.
__global__ __launch_bounds__(256) void expand_kernel(
    const u16* __restrict__ Et, const float* __restrict__ invs, float* __restrict__ attn)
{
    const int xc = blockIdx.x;            // 16-row chunk
    const int bh = blockIdx.y;
    const int qt = xc >> 2;
    const int r0 = (xc & 3) * 16;         // row base within the 64-row tile
    const int t = threadIdx.x;
    const int kt = t >> 3;                // 0..31 key tile
    const int cc = (t & 7) * 8;           // col within tile
    const u16* tb = Et + (((size_t)bh * 32 + qt) << 17) + (kt << 12) + cc;
    const int m0 = qt * 64 + r0;
    float* ab = attn + ((((size_t)bh << 11) + m0) << 11) + kt*64 + cc;
    const float* ivp = invs + ((size_t)bh << 11) + m0;

    #pragma unroll
    for (int rr = 0; rr < 16; rr += 4) {
        bf16x8 e0 = *(const bf16x8*)(tb + (r0+rr+0)*64);
        bf16x8 e1 = *(const bf16x8*)(tb + (r0+rr+1)*64);
        bf16x8 e2 = *(const bf16x8*)(tb + (r0+rr+2)*64);
        bf16x8 e3 = *(const bf16x8*)(tb + (r0+rr+3)*64);
        const float i0 = ivp[rr+0], i1 = ivp[rr+1], i2 = ivp[rr+2], i3 = ivp[rr+3];
        f32x4 lo, hi;
        #pragma unroll
        for (int jj = 0; jj < 4; ++jj) { lo[jj] = bf2f((u16)e0[jj]) * i0; hi[jj] = bf2f((u16)e0[jj+4]) * i0; }
        *(f32x4*)(ab + (size_t)(rr+0)*2048)     = lo;
        *(f32x4*)(ab + (size_t)(rr+0)*2048 + 4) = hi;
        #pragma unroll
        for (int jj = 0; jj < 4; ++jj) { lo[jj] = bf2f((u16)e1[jj]) * i1; hi[jj] = bf2f((u16)e1[jj+4]) * i1; }
        *(f32x4*)(ab + (size_t)(rr+1)*2048)     = lo;
        *(f32x4*)(ab + (size_t)(rr+1)*2048 + 4) = hi;
        #pragma unroll
        for (int jj = 0; jj < 4; ++jj) { lo[jj] = bf2f((u16)e2[jj]) * i2; hi[jj] = bf2f((u16)e2[jj+4]) * i2; }
        *(f32x4*)(ab + (size_t)(rr+2)*2048)     = lo;
        *(f32x4*)(ab + (size_t)(rr+2)*2048 + 4) = hi;
        #pragma unroll
        for (int jj = 0; jj < 4; ++jj) { lo[jj] = bf2f((u16)e3[jj]) * i3; hi[jj] = bf2f((u16)e3[jj+4]) * i3; }
        *(f32x4*)(ab + (size_t)(rr+3)*2048)     = lo;
        *(f32x4*)(ab + (size_t)(rr+3)*2048 + 4) = hi;
    }
}

// ---------------- K4: out = heads(bf16) @ wo + q residual ----------------
__global__ __launch_bounds__(256) void outgemm_kernel(
    const u16* __restrict__ heads, const u16* __restrict__ wt,
    const float* __restrict__ qin, float* __restrict__ out)
{
    const int m0 = blockIdx.x * 64, n0b = blockIdx.y * 64;
    const int t = threadIdx.x, l = t & 63, w = t >> 6;
    const int q = l & 15, G = l >> 4;
    const int wr = w >> 1, wc = w & 1;
    const u16* W = wt + (size_t)3 * 512 * 512;
    f32x4 acc[2][2] = {};
    for (int k0 = 0; k0 < 512; k0 += 32) {
        bf16x8 af[2], bfr[2];
        #pragma unroll
        for (int mi = 0; mi < 2; ++mi)
            af[mi] = *(const bf16x8*)(heads + (size_t)(m0 + wr*32 + mi*16 + q) * 512 + k0 + G*8);
        #pragma unroll
        for (int tn = 0; tn < 2; ++tn)
            bfr[tn] = *(const bf16x8*)(W + (size_t)(n0b + wc*32 + tn*16 + q) * 512 + k0 + G*8);
        #pragma unroll
        for (int mi = 0; mi < 2; ++mi)
            #pragma unroll
            for (int tn = 0; tn < 2; ++tn)
                acc[mi][tn] = MFMA16(af[mi], bfr[tn], acc[mi][tn], 0, 0, 0);
    }
    #pragma unroll
    for (int mi = 0; mi < 2; ++mi)
        #pragma unroll
        for (int r = 0; r < 4; ++r) {
            const int m = m0 + wr*32 + mi*16 + G*4 + r;
            #pragma unroll
            for (int tn = 0; tn < 2; ++tn) {
                const int n = n0b + wc*32 + tn*16 + q;
                out[(size_t)m * 512 + n] = acc[mi][tn][r] + qin[(size_t)m * 512 + n];
            }
        }
}

// ---------------- K5: in-place row LayerNorm ----------------
__global__ __launch_bounds__(256) void ln_kernel(
    float* __restrict__ out, const float* __restrict__ g, const float* __restrict__ be)
{
    const int m = blockIdx.x;
    float* row = out + (size_t)m * 512;
    const int t = threadIdx.x;
    float2 v = ((const float2*)row)[t];
    float s  = block_sum256(v.x + v.y);
    float s2 = block_sum256(v.x * v.x + v.y * v.y);
    const float mu  = s * (1.0f / 512.0f);
    const float var = s2 * (1.0f / 512.0f) - mu * mu;
    const float inv = rsqrtf(var + LN_EPS);
    float2 gg = ((const float2*)g)[t];
    float2 bb = ((const float2*)be)[t];
    float2 r;
    r.x = (v.x - mu) * inv * gg.x + bb.x;
    r.y = (v.y - mu) * inv * gg.y + bb.y;
    ((float2*)row)[t] = r;
}

// ---------------- launch ----------------
extern "C" void kernel_launch(void* const* d_in, const int* in_sizes, int n_in,
                              void* d_out, int out_size, void* d_ws, size_t ws_size,
                              hipStream_t stream) {
    const float* q   = (const float*)d_in[0];
    const float* k   = (const float*)d_in[1];
    const float* v   = (const float*)d_in[2];
    const float* wq  = (const float*)d_in[3];
    const float* wk  = (const float*)d_in[4];
    const float* wv  = (const float*)d_in[5];
    const float* wo  = (const float*)d_in[6];
    const float* g   = (const float*)d_in[7];
    const float* be  = (const float*)d_in[8];
    const int*   msk = (const int*)d_in[9];

    float* out  = (float*)d_out;
    float* attn = out + (size_t)4 * 2048 * 512;

    const size_t nQKV = (size_t)32 * 2048 * 64;          // 4M u16 per tensor
    u16* Qh    = (u16*)d_ws;
    u16* Kh    = Qh + nQKV;
    u16* Vh    = Kh + nQKV;
    u16* Vt    = Vh + nQKV;
    u16* heads = Vt + nQKV;
    u16* wt    = heads + (size_t)8192 * 512;
    u64* bits  = (u64*)(wt + (size_t)4 * 512 * 512);
    float* invs = (float*)(bits + (size_t)8192 * 32);    // 65536 f32
    u16* Et     = (u16*)(invs + 65536);                  // 32*32*32*4096 bf16 = 268MB

    prepw_kernel  <<<dim3(8, 8, 4),    256, 0, stream>>>(wq, wk, wv, wo, wt);
    prepm_kernel  <<<dim3(2048),       256, 0, stream>>>(msk, bits);
    proj_kernel   <<<dim3(128, 8, 3),  256, 0, stream>>>(q, k, v, wt, Qh, Kh, Vh);
    vt_kernel     <<<dim3(32, 32),     256, 0, stream>>>(Vh, Vt);
    attnpv_kernel <<<dim3(1024),       256, 0, stream>>>(Qh, Kh, Vt, bits, Et, invs, heads);
    expand_kernel <<<dim3(128, 32),    256, 0, stream>>>(Et, invs, attn);
    outgemm_kernel<<<dim3(128, 8),     256, 0, stream>>>(heads, wt, q, out);
    ln_kernel     <<<dim3(8192),       256, 0, stream>>>(out, g, be);
}

// Round 9
// 576.711 us; speedup vs baseline: 1.2874x; 1.1325x over previous
//
#include <hip/hip_runtime.h>
#include <cstddef>

typedef __attribute__((ext_vector_type(8))) short bf16x8;
typedef __attribute__((ext_vector_type(4))) float f32x4;
typedef __attribute__((ext_vector_type(4))) short short4v;
typedef unsigned long long u64;
typedef unsigned int u32;
typedef unsigned short u16;

#define MFMA16 __builtin_amdgcn_mfma_f32_16x16x32_bf16
static constexpr float LN_EPS = 1e-5f;
static constexpr float L2E = 1.44269504f;

__device__ __forceinline__ u16 f2bf(float f) {
    u32 u = __builtin_bit_cast(u32, f);
    return (u16)((u + 0x7FFFu + ((u >> 16) & 1u)) >> 16);
}
__device__ __forceinline__ float bf2f(u16 h) {
    u32 u = ((u32)h) << 16;
    return __builtin_bit_cast(float, u);
}

// ---------------- block-wide sum (256 threads) ----------------
__device__ __forceinline__ float block_sum256(float v) {
    __shared__ float sc[4];
    #pragma unroll
    for (int o = 32; o > 0; o >>= 1) v += __shfl_down(v, o);
    if ((threadIdx.x & 63) == 0) sc[threadIdx.x >> 6] = v;
    __syncthreads();
    v = sc[0] + sc[1] + sc[2] + sc[3];
    __syncthreads();
    return v;
}

// ---------------- prep: weights fp32 [k][n] -> bf16 Wt [mat][n][k] ----------------
__global__ __launch_bounds__(256) void prepw_kernel(
    const float* __restrict__ wq, const float* __restrict__ wk,
    const float* __restrict__ wv, const float* __restrict__ wo,
    u16* __restrict__ wt)
{
    const int mat = blockIdx.z;
    const float* W = mat == 0 ? wq : mat == 1 ? wk : mat == 2 ? wv : wo;
    const int k0 = blockIdx.x * 64, n0 = blockIdx.y * 64;
    __shared__ u16 ld[64][72];
    const int t = threadIdx.x;
    {
        const int kk = t >> 2;
        #pragma unroll
        for (int j = 0; j < 4; ++j) {
            const int nn = ((t & 3) + j * 4) * 4;
            float4 x = *(const float4*)&W[(size_t)(k0 + kk) * 512 + n0 + nn];
            ld[kk][nn + 0] = f2bf(x.x); ld[kk][nn + 1] = f2bf(x.y);
            ld[kk][nn + 2] = f2bf(x.z); ld[kk][nn + 3] = f2bf(x.w);
        }
    }
    __syncthreads();
    {
        const int n = t & 63, kc = (t >> 6) * 16;
        u16* op = wt + ((size_t)mat * 512 + n0 + n) * 512 + k0 + kc;
        #pragma unroll
        for (int j = 0; j < 4; ++j) {
            short4v v;
            v[0] = ld[kc + j*4 + 0][n]; v[1] = ld[kc + j*4 + 1][n];
            v[2] = ld[kc + j*4 + 2][n]; v[3] = ld[kc + j*4 + 3][n];
            *(short4v*)(op + j * 4) = v;
        }
    }
}

// ---------------- prep: mask int32 -> bit-packed u64 [8192 rows][32 words] ----------------
__global__ __launch_bounds__(256) void prepm_kernel(
    const int* __restrict__ mask, u64* __restrict__ bits)
{
    const int t = threadIdx.x;
    const int row = blockIdx.x * 4 + (t >> 6);
    const int wl = t & 63;
    const int* mrow = mask + (size_t)row * 2048;
    u64* brow = bits + (size_t)row * 32;
    #pragma unroll 8
    for (int it = 0; it < 32; ++it) {
        u64 b = __ballot(mrow[it * 64 + wl] != 0);
        if (wl == 0) brow[it] = b;
    }
}

// ---------------- K1: projections via MFMA. X fp32 @ Wt -> Qh/Kh/Vh bf16 [bh][s][64]
__global__ __launch_bounds__(256) void proj_kernel(
    const float* __restrict__ qin, const float* __restrict__ kin, const float* __restrict__ vin,
    const u16* __restrict__ wt,
    u16* __restrict__ Qh, u16* __restrict__ Kh, u16* __restrict__ Vh)
{
    const int z = blockIdx.z;
    const float* X = z == 0 ? qin : (z == 1 ? kin : vin);
    const u16* W = wt + (size_t)z * 512 * 512;
    u16* O = z == 0 ? Qh : (z == 1 ? Kh : Vh);
    const int m0 = blockIdx.x * 64;
    const int h = blockIdx.y;
    const int t = threadIdx.x, l = t & 63, w = t >> 6;
    const int q = l & 15, G = l >> 4;
    const int wr = w >> 1, wc = w & 1;

    f32x4 acc[2][2] = {};
    for (int k0 = 0; k0 < 512; k0 += 32) {
        bf16x8 af[2], bfr[2];
        #pragma unroll
        for (int mi = 0; mi < 2; ++mi) {
            const float* xp = X + (size_t)(m0 + wr*32 + mi*16 + q) * 512 + k0 + G*8;
            float4 x0 = *(const float4*)xp;
            float4 x1 = *(const float4*)(xp + 4);
            bf16x8 a;
            a[0] = f2bf(x0.x); a[1] = f2bf(x0.y); a[2] = f2bf(x0.z); a[3] = f2bf(x0.w);
            a[4] = f2bf(x1.x); a[5] = f2bf(x1.y); a[6] = f2bf(x1.z); a[7] = f2bf(x1.w);
            af[mi] = a;
        }
        #pragma unroll
        for (int tn = 0; tn < 2; ++tn)
            bfr[tn] = *(const bf16x8*)(W + (size_t)(h*64 + wc*32 + tn*16 + q) * 512 + k0 + G*8);
        #pragma unroll
        for (int mi = 0; mi < 2; ++mi)
            #pragma unroll
            for (int tn = 0; tn < 2; ++tn)
                acc[mi][tn] = MFMA16(af[mi], bfr[tn], acc[mi][tn], 0, 0, 0);
    }
    const float scv = (z == 0) ? 0.125f : 1.0f;   // fold 1/sqrt(64) into Q (exact pow2)
    #pragma unroll
    for (int mi = 0; mi < 2; ++mi)
        #pragma unroll
        for (int tn = 0; tn < 2; ++tn)
            #pragma unroll
            for (int r = 0; r < 4; ++r) {
                const int m = m0 + wr*32 + mi*16 + G*4 + r;
                const int b = m >> 11, s = m & 2047;
                const int d = wc*32 + tn*16 + q;
                O[(((size_t)(b*8 + h) << 11) + s) * 64 + d] = f2bf(acc[mi][tn][r] * scv);
            }
}

// ---------------- V transpose: Vh [bh][s][64] -> Vt [bh][64][2048] ----------------
__global__ __launch_bounds__(256) void vt_kernel(
    const u16* __restrict__ Vh, u16* __restrict__ Vt)
{
    const int bh = blockIdx.y, s0 = blockIdx.x * 64;
    __shared__ u16 ld[64][72];
    const int t = threadIdx.x;
    {
        const int s = t >> 2, dg = (t & 3) * 16;
        const u16* vp = Vh + ((((size_t)bh << 11) + s0 + s) * 64) + dg;
        *(bf16x8*)&ld[s][dg]     = *(const bf16x8*)vp;
        *(bf16x8*)&ld[s][dg + 8] = *(const bf16x8*)(vp + 8);
    }
    __syncthreads();
    {
        const int d = t & 63, sc = (t >> 6) * 16;
        u16* op = Vt + (((size_t)bh << 6) + d) * 2048 + s0 + sc;
        #pragma unroll
        for (int j = 0; j < 4; ++j) {
            short4v v;
            v[0] = ld[sc + j*4 + 0][d]; v[1] = ld[sc + j*4 + 1][d];
            v[2] = ld[sc + j*4 + 2][d]; v[3] = ld[sc + j*4 + 3][d];
            *(short4v*)(op + j * 4) = v;
        }
    }
}

// ---------------- fused attn: 2-phase LDS-staged QK^T -> exp -> {rowsum, Et store, PV} ----------------
// grid 1024 (XCD-swizzled). K/V tiles double-buffered in LDS (XOR-swizzled); reg-staged
// (loads issued at iteration top, ds_write at bottom -> latency hides under compute).
__global__ __launch_bounds__(256) void attnpv_kernel(
    const u16* __restrict__ Qh, const u16* __restrict__ Kh, const u16* __restrict__ Vt,
    const u64* __restrict__ bits,
    u16* __restrict__ Et, float* __restrict__ invs, u16* __restrict__ heads)
{
    const int j   = blockIdx.x;
    const int lid = (j & 7) * 128 + (j >> 3);     // XCD-contiguous bh ranges
    const int qt = lid & 31, bh = lid >> 5;
    const int b = bh >> 3, h = bh & 7;
    const int m0 = qt * 64;
    const int t = threadIdx.x, l = t & 63, w = t >> 6;
    const int q = l & 15, G = l >> 4;
    const int qrow = m0 + w*16 + q;
    __shared__ u16 kbuf[2][4096];          // 64x64 bf16 K tile, XOR-swizzled rows
    __shared__ u16 vbuf[2][4096];          // 64x64 bf16 V^T tile
    __shared__ u16 alds[4][1024];          // per-wave 16x64 E tile
    u16* my = alds[w];

    const size_t qbase = (((size_t)bh << 11) + qrow) * 64;
    bf16x8 qf0 = *(const bf16x8*)(Qh + qbase + G*8);
    bf16x8 qf1 = *(const bf16x8*)(Qh + qbase + 32 + G*8);
    const u64* brow = bits + (((size_t)b << 11) + qrow) * 32;
    const int swz = (q & 7) << 3;
    const int sr  = l >> 2;
    const int c16 = (l & 3) * 16;
    const int ssw = (sr & 7) << 3;
    u16* etq = Et + (((size_t)bh * 32 + qt) << 17);

    // staging geometry: thread covers rows srow0 (i=0) and srow0+32 (i=1), 16B each
    const int srow0 = t >> 3;
    const int scol  = (t & 7) * 8;
    const u16* Kbase = Kh + (((size_t)bh << 11) * 64);
    const u16* Vbase = Vt + (((size_t)bh << 6) * 2048);
    const int eswz = (t * 8) ^ ((srow0 & 7) << 3);   // swizzled dest element (i=0); i=1: +2048

    bf16x8 sk0, sk1, sv0, sv1;
    float rs = 0.f;
    f32x4 pacc[4] = {};

    // prologue: stage tile 0
    {
        const u16* kp = Kbase + (size_t)srow0 * 64 + scol;
        sk0 = *(const bf16x8*)kp;
        sk1 = *(const bf16x8*)(kp + 32 * 64);
        const u16* vp = Vbase + (size_t)srow0 * 2048 + scol;
        sv0 = *(const bf16x8*)vp;
        sv1 = *(const bf16x8*)(vp + 32 * 2048);
        *(bf16x8*)&kbuf[0][eswz]        = sk0;
        *(bf16x8*)&kbuf[0][2048 + eswz] = sk1;
        *(bf16x8*)&vbuf[0][eswz]        = sv0;
        *(bf16x8*)&vbuf[0][2048 + eswz] = sv1;
    }
    __syncthreads();

    for (int kt = 0; kt < 32; ++kt) {
        const int cur = kt & 1;
        if (kt < 31) {                      // issue next-tile loads early
            const int n1 = (kt + 1) * 64;
            const u16* kp = Kbase + (size_t)(n1 + srow0) * 64 + scol;
            sk0 = *(const bf16x8*)kp;
            sk1 = *(const bf16x8*)(kp + 32 * 64);
            const u16* vp = Vbase + (size_t)srow0 * 2048 + n1 + scol;
            sv0 = *(const bf16x8*)vp;
            sv1 = *(const bf16x8*)(vp + 32 * 2048);
        }
        // QK^T from LDS
        f32x4 acc[4] = {};
        #pragma unroll
        for (int mt = 0; mt < 4; ++mt) {
            const int r = mt*16 + q;
            const int rsw = (r & 7) << 3;
            bf16x8 k0 = *(const bf16x8*)&kbuf[cur][(r*64 +      G*8) ^ rsw];
            bf16x8 k1 = *(const bf16x8*)&kbuf[cur][(r*64 + 32 + G*8) ^ rsw];
            acc[mt] = MFMA16(k0, qf0, acc[mt], 0, 0, 0);
            acc[mt] = MFMA16(k1, qf1, acc[mt], 0, 0, 0);
        }
        const u64 mw = brow[kt];
        #pragma unroll
        for (int mt = 0; mt < 4; ++mt) {
            short4v sv;
            #pragma unroll
            for (int r = 0; r < 4; ++r) {
                const int c = mt*16 + G*4 + r;
                const float e = ((mw >> c) & 1) ? 0.f : exp2f(acc[mt][r] * L2E);
                rs += e;
                sv[r] = (short)f2bf(e);
            }
            *(short4v*)&my[(q*64 + mt*16 + G*4) ^ swz] = sv;
        }
        bf16x8 an0 = *(const bf16x8*)&my[(q*64 +  0 + G*8) ^ swz];
        bf16x8 an1 = *(const bf16x8*)&my[(q*64 + 32 + G*8) ^ swz];
        // E tile store: wave writes its 16x64 tile as contiguous 2KB
        {
            u16* et = etq + (kt << 12) + (w * 16) * 64;
            bf16x8 e0 = *(const bf16x8*)&my[sr*64 + ((c16 + 0) ^ ssw)];
            bf16x8 e1 = *(const bf16x8*)&my[sr*64 + ((c16 + 8) ^ ssw)];
            *(bf16x8*)(et + sr*64 + c16)     = e0;
            *(bf16x8*)(et + sr*64 + c16 + 8) = e1;
        }
        // PV from LDS
        #pragma unroll
        for (int dmt = 0; dmt < 4; ++dmt) {
            const int r = dmt*16 + q;
            const int rsw = (r & 7) << 3;
            bf16x8 v0 = *(const bf16x8*)&vbuf[cur][(r*64 +      G*8) ^ rsw];
            bf16x8 v1 = *(const bf16x8*)&vbuf[cur][(r*64 + 32 + G*8) ^ rsw];
            pacc[dmt] = MFMA16(v0, an0, pacc[dmt], 0, 0, 0);
            pacc[dmt] = MFMA16(v1, an1, pacc[dmt], 0, 0, 0);
        }
        // write staged tile kt+1 into the other buffer
        if (kt < 31) {
            const int nxt = cur ^ 1;
            *(bf16x8*)&kbuf[nxt][eswz]        = sk0;
            *(bf16x8*)&kbuf[nxt][2048 + eswz] = sk1;
            *(bf16x8*)&vbuf[nxt][eswz]        = sv0;
            *(bf16x8*)&vbuf[nxt][2048 + eswz] = sv1;
        }
        __syncthreads();
    }
    // row sums -> inv (reduce over the 4 G-groups holding the same q-row)
    rs += __shfl_xor(rs, 16);
    rs += __shfl_xor(rs, 32);
    const float inv = 1.0f / rs;
    if (G == 0) invs[((size_t)bh << 11) + qrow] = inv;
    #pragma unroll
    for (int dmt = 0; dmt < 4; ++dmt) {
        short4v sv;
        #pragma unroll
        for (int r = 0; r < 4; ++r) sv[r] = (short)f2bf(pacc[dmt][r] * inv);
        *(short4v*)&heads[(((size_t)b << 11) + qrow) * 512 + h*64 + dmt*16 + G*4] = sv;
    }
}

// ---------------- expand: attn[f32 row-major] = Et[tiled bf16] * invs ----------------
// grid (128 row-chunks, 32 bh). Pure streaming: coalesced 16B reads, 8KB-row writes.
__global__ __launch_bounds__(256) void expand_kernel(
    const u16* __restrict__ Et, const float* __restrict__ invs, float* __restrict__ attn)
{
    const int xc = blockIdx.x;            // 16-row chunk
    const int bh = blockIdx.y;
    const int qt = xc >> 2;
    const int r0 = (xc & 3) * 16;         // row base within the 64-row tile
    const int t = threadIdx.x;
    const int kt = t >> 3;                // 0..31 key tile
    const int cc = (t & 7) * 8;           // col within tile
    const u16* tb = Et + (((size_t)bh * 32 + qt) << 17) + (kt << 12) + cc;
    const int m0 = qt * 64 + r0;
    float* ab = attn + ((((size_t)bh << 11) + m0) << 11) + kt*64 + cc;
    const float* ivp = invs + ((size_t)bh << 11) + m0;

    #pragma unroll
    for (int rr = 0; rr < 16; rr += 4) {
        bf16x8 e0 = *(const bf16x8*)(tb + (r0+rr+0)*64);
        bf16x8 e1 = *(const bf16x8*)(tb + (r0+rr+1)*64);
        bf16x8 e2 = *(const bf16x8*)(tb + (r0+rr+2)*64);
        bf16x8 e3 = *(const bf16x8*)(tb + (r0+rr+3)*64);
        const float i0 = ivp[rr+0], i1 = ivp[rr+1], i2 = ivp[rr+2], i3 = ivp[rr+3];
        f32x4 lo, hi;
        #pragma unroll
        for (int jj = 0; jj < 4; ++jj) { lo[jj] = bf2f((u16)e0[jj]) * i0; hi[jj] = bf2f((u16)e0[jj+4]) * i0; }
        *(f32x4*)(ab + (size_t)(rr+0)*2048)     = lo;
        *(f32x4*)(ab + (size_t)(rr+0)*2048 + 4) = hi;
        #pragma unroll
        for (int jj = 0; jj < 4; ++jj) { lo[jj] = bf2f((u16)e1[jj]) * i1; hi[jj] = bf2f((u16)e1[jj+4]) * i1; }
        *(f32x4*)(ab + (size_t)(rr+1)*2048)     = lo;
        *(f32x4*)(ab + (size_t)(rr+1)*2048 + 4) = hi;
        #pragma unroll
        for (int jj = 0; jj < 4; ++jj) { lo[jj] = bf2f((u16)e2[jj]) * i2; hi[jj] = bf2f((u16)e2[jj+4]) * i2; }
        *(f32x4*)(ab + (size_t)(rr+2)*2048)     = lo;
        *(f32x4*)(ab + (size_t)(rr+2)*2048 + 4) = hi;
        #pragma unroll
        for (int jj = 0; jj < 4; ++jj) { lo[jj] = bf2f((u16)e3[jj]) * i3; hi[jj] = bf2f((u16)e3[jj+4]) * i3; }
        *(f32x4*)(ab + (size_t)(rr+3)*2048)     = lo;
        *(f32x4*)(ab + (size_t)(rr+3)*2048 + 4) = hi;
    }
}

// ---------------- K4: out = heads(bf16) @ wo + q residual ----------------
__global__ __launch_bounds__(256) void outgemm_kernel(
    const u16* __restrict__ heads, const u16* __restrict__ wt,
    const float* __restrict__ qin, float* __restrict__ out)
{
    const int m0 = blockIdx.x * 64, n0b = blockIdx.y * 64;
    const int t = threadIdx.x, l = t & 63, w = t >> 6;
    const int q = l & 15, G = l >> 4;
    const int wr = w >> 1, wc = w & 1;
    const u16* W = wt + (size_t)3 * 512 * 512;
    f32x4 acc[2][2] = {};
    for (int k0 = 0; k0 < 512; k0 += 32) {
        bf16x8 af[2], bfr[2];
        #pragma unroll
        for (int mi = 0; mi < 2; ++mi)
            af[mi] = *(const bf16x8*)(heads + (size_t)(m0 + wr*32 + mi*16 + q) * 512 + k0 + G*8);
        #pragma unroll
        for (int tn = 0; tn < 2; ++tn)
            bfr[tn] = *(const bf16x8*)(W + (size_t)(n0b + wc*32 + tn*16 + q) * 512 + k0 + G*8);
        #pragma unroll
        for (int mi = 0; mi < 2; ++mi)
            #pragma unroll
            for (int tn = 0; tn < 2; ++tn)
                acc[mi][tn] = MFMA16(af[mi], bfr[tn], acc[mi][tn], 0, 0, 0);
    }
    #pragma unroll
    for (int mi = 0; mi < 2; ++mi)
        #pragma unroll
        for (int r = 0; r < 4; ++r) {
            const int m = m0 + wr*32 + mi*16 + G*4 + r;
            #pragma unroll
            for (int tn = 0; tn < 2; ++tn) {
                const int n = n0b + wc*32 + tn*16 + q;
                out[(size_t)m * 512 + n] = acc[mi][tn][r] + qin[(size_t)m * 512 + n];
            }
        }
}

// ---------------- K5: in-place row LayerNorm ----------------
__global__ __launch_bounds__(256) void ln_kernel(
    float* __restrict__ out, const float* __restrict__ g, const float* __restrict__ be)
{
    const int m = blockIdx.x;
    float* row = out + (size_t)m * 512;
    const int t = threadIdx.x;
    float2 v = ((const float2*)row)[t];
    float s  = block_sum256(v.x + v.y);
    float s2 = block_sum256(v.x * v.x + v.y * v.y);
    const float mu  = s * (1.0f / 512.0f);
    const float var = s2 * (1.0f / 512.0f) - mu * mu;
    const float inv = rsqrtf(var + LN_EPS);
    float2 gg = ((const float2*)g)[t];
    float2 bb = ((const float2*)be)[t];
    float2 r;
    r.x = (v.x - mu) * inv * gg.x + bb.x;
    r.y = (v.y - mu) * inv * gg.y + bb.y;
    ((float2*)row)[t] = r;
}

// ---------------- launch ----------------
extern "C" void kernel_launch(void* const* d_in, const int* in_sizes, int n_in,
                              void* d_out, int out_size, void* d_ws, size_t ws_size,
                              hipStream_t stream) {
    const float* q   = (const float*)d_in[0];
    const float* k   = (const float*)d_in[1];
    const float* v   = (const float*)d_in[2];
    const float* wq  = (const float*)d_in[3];
    const float* wk  = (const float*)d_in[4];
    const float* wv  = (const float*)d_in[5];
    const float* wo  = (const float*)d_in[6];
    const float* g   = (const float*)d_in[7];
    const float* be  = (const float*)d_in[8];
    const int*   msk = (const int*)d_in[9];

    float* out  = (float*)d_out;
    float* attn = out + (size_t)4 * 2048 * 512;

    const size_t nQKV = (size_t)32 * 2048 * 64;          // 4M u16 per tensor
    u16* Qh    = (u16*)d_ws;
    u16* Kh    = Qh + nQKV;
    u16* Vh    = Kh + nQKV;
    u16* Vt    = Vh + nQKV;
    u16* heads = Vt + nQKV;
    u16* wt    = heads + (size_t)8192 * 512;
    u64* bits  = (u64*)(wt + (size_t)4 * 512 * 512);
    float* invs = (float*)(bits + (size_t)8192 * 32);    // 65536 f32
    u16* Et     = (u16*)(invs + 65536);                  // 32*32*32*4096 bf16 = 268MB

    prepw_kernel  <<<dim3(8, 8, 4),    256, 0, stream>>>(wq, wk, wv, wo, wt);
    prepm_kernel  <<<dim3(2048),       256, 0, stream>>>(msk, bits);
    proj_kernel   <<<dim3(128, 8, 3),  256, 0, stream>>>(q, k, v, wt, Qh, Kh, Vh);
    vt_kernel     <<<dim3(32, 32),     256, 0, stream>>>(Vh, Vt);
    attnpv_kernel <<<dim3(1024),       256, 0, stream>>>(Qh, Kh, Vt, bits, Et, invs, heads);
    expand_kernel <<<dim3(128, 32),    256, 0, stream>>>(Et, invs, attn);
    outgemm_kernel<<<dim3(128, 8),     256, 0, stream>>>(heads, wt, q, out);
    ln_kernel     <<<dim3(8192),       256, 0, stream>>>(out, g, be);
}

// Round 10
// 502.101 us; speedup vs baseline: 1.4787x; 1.1486x over previous
//
#include <hip/hip_runtime.h>
#include <cstddef>

typedef __attribute__((ext_vector_type(8))) short bf16x8;
typedef __attribute__((ext_vector_type(4))) float f32x4;
typedef __attribute__((ext_vector_type(4))) short short4v;
typedef unsigned long long u64;
typedef unsigned int u32;
typedef unsigned short u16;

#define MFMA16 __builtin_amdgcn_mfma_f32_16x16x32_bf16
static constexpr float LN_EPS = 1e-5f;
static constexpr float L2E = 1.44269504f;

__device__ __forceinline__ u16 f2bf(float f) {
    u32 u = __builtin_bit_cast(u32, f);
    return (u16)((u + 0x7FFFu + ((u >> 16) & 1u)) >> 16);
}
__device__ __forceinline__ float bf2f(u16 h) {
    u32 u = ((u32)h) << 16;
    return __builtin_bit_cast(float, u);
}

// ---------------- block-wide sum (256 threads) ----------------
__device__ __forceinline__ float block_sum256(float v) {
    __shared__ float sc[4];
    #pragma unroll
    for (int o = 32; o > 0; o >>= 1) v += __shfl_down(v, o);
    if ((threadIdx.x & 63) == 0) sc[threadIdx.x >> 6] = v;
    __syncthreads();
    v = sc[0] + sc[1] + sc[2] + sc[3];
    __syncthreads();
    return v;
}

// ---------------- prep: weights fp32 [k][n] -> bf16 Wt [mat][n][k] ----------------
__global__ __launch_bounds__(256) void prepw_kernel(
    const float* __restrict__ wq, const float* __restrict__ wk,
    const float* __restrict__ wv, const float* __restrict__ wo,
    u16* __restrict__ wt)
{
    const int mat = blockIdx.z;
    const float* W = mat == 0 ? wq : mat == 1 ? wk : mat == 2 ? wv : wo;
    const int k0 = blockIdx.x * 64, n0 = blockIdx.y * 64;
    __shared__ u16 ld[64][72];
    const int t = threadIdx.x;
    {
        const int kk = t >> 2;
        #pragma unroll
        for (int j = 0; j < 4; ++j) {
            const int nn = ((t & 3) + j * 4) * 4;
            float4 x = *(const float4*)&W[(size_t)(k0 + kk) * 512 + n0 + nn];
            ld[kk][nn + 0] = f2bf(x.x); ld[kk][nn + 1] = f2bf(x.y);
            ld[kk][nn + 2] = f2bf(x.z); ld[kk][nn + 3] = f2bf(x.w);
        }
    }
    __syncthreads();
    {
        const int n = t & 63, kc = (t >> 6) * 16;
        u16* op = wt + ((size_t)mat * 512 + n0 + n) * 512 + k0 + kc;
        #pragma unroll
        for (int j = 0; j < 4; ++j) {
            short4v v;
            v[0] = ld[kc + j*4 + 0][n]; v[1] = ld[kc + j*4 + 1][n];
            v[2] = ld[kc + j*4 + 2][n]; v[3] = ld[kc + j*4 + 3][n];
            *(short4v*)(op + j * 4) = v;
        }
    }
}

// ---------------- prep: mask int32 -> bit-packed u64 [8192 rows][32 words] ----------------
__global__ __launch_bounds__(256) void prepm_kernel(
    const int* __restrict__ mask, u64* __restrict__ bits)
{
    const int t = threadIdx.x;
    const int row = blockIdx.x * 4 + (t >> 6);
    const int wl = t & 63;
    const int* mrow = mask + (size_t)row * 2048;
    u64* brow = bits + (size_t)row * 32;
    #pragma unroll 8
    for (int it = 0; it < 32; ++it) {
        u64 b = __ballot(mrow[it * 64 + wl] != 0);
        if (wl == 0) brow[it] = b;
    }
}

// ---------------- K1: projections via MFMA. X fp32 @ Wt -> Qh/Kh/Vh bf16 [bh][s][64]
__global__ __launch_bounds__(256) void proj_kernel(
    const float* __restrict__ qin, const float* __restrict__ kin, const float* __restrict__ vin,
    const u16* __restrict__ wt,
    u16* __restrict__ Qh, u16* __restrict__ Kh, u16* __restrict__ Vh)
{
    const int z = blockIdx.z;
    const float* X = z == 0 ? qin : (z == 1 ? kin : vin);
    const u16* W = wt + (size_t)z * 512 * 512;
    u16* O = z == 0 ? Qh : (z == 1 ? Kh : Vh);
    const int m0 = blockIdx.x * 64;
    const int h = blockIdx.y;
    const int t = threadIdx.x, l = t & 63, w = t >> 6;
    const int q = l & 15, G = l >> 4;
    const int wr = w >> 1, wc = w & 1;

    f32x4 acc[2][2] = {};
    for (int k0 = 0; k0 < 512; k0 += 32) {
        bf16x8 af[2], bfr[2];
        #pragma unroll
        for (int mi = 0; mi < 2; ++mi) {
            const float* xp = X + (size_t)(m0 + wr*32 + mi*16 + q) * 512 + k0 + G*8;
            float4 x0 = *(const float4*)xp;
            float4 x1 = *(const float4*)(xp + 4);
            bf16x8 a;
            a[0] = f2bf(x0.x); a[1] = f2bf(x0.y); a[2] = f2bf(x0.z); a[3] = f2bf(x0.w);
            a[4] = f2bf(x1.x); a[5] = f2bf(x1.y); a[6] = f2bf(x1.z); a[7] = f2bf(x1.w);
            af[mi] = a;
        }
        #pragma unroll
        for (int tn = 0; tn < 2; ++tn)
            bfr[tn] = *(const bf16x8*)(W + (size_t)(h*64 + wc*32 + tn*16 + q) * 512 + k0 + G*8);
        #pragma unroll
        for (int mi = 0; mi < 2; ++mi)
            #pragma unroll
            for (int tn = 0; tn < 2; ++tn)
                acc[mi][tn] = MFMA16(af[mi], bfr[tn], acc[mi][tn], 0, 0, 0);
    }
    const float scv = (z == 0) ? 0.125f : 1.0f;   // fold 1/sqrt(64) into Q (exact pow2)
    #pragma unroll
    for (int mi = 0; mi < 2; ++mi)
        #pragma unroll
        for (int tn = 0; tn < 2; ++tn)
            #pragma unroll
            for (int r = 0; r < 4; ++r) {
                const int m = m0 + wr*32 + mi*16 + G*4 + r;
                const int b = m >> 11, s = m & 2047;
                const int d = wc*32 + tn*16 + q;
                O[(((size_t)(b*8 + h) << 11) + s) * 64 + d] = f2bf(acc[mi][tn][r] * scv);
            }
}

// ---------------- V transpose: Vh [bh][s][64] -> Vt [bh][64][2048] ----------------
__global__ __launch_bounds__(256) void vt_kernel(
    const u16* __restrict__ Vh, u16* __restrict__ Vt)
{
    const int bh = blockIdx.y, s0 = blockIdx.x * 64;
    __shared__ u16 ld[64][72];
    const int t = threadIdx.x;
    {
        const int s = t >> 2, dg = (t & 3) * 16;
        const u16* vp = Vh + ((((size_t)bh << 11) + s0 + s) * 64) + dg;
        *(bf16x8*)&ld[s][dg]     = *(const bf16x8*)vp;
        *(bf16x8*)&ld[s][dg + 8] = *(const bf16x8*)(vp + 8);
    }
    __syncthreads();
    {
        const int d = t & 63, sc = (t >> 6) * 16;
        u16* op = Vt + (((size_t)bh << 6) + d) * 2048 + s0 + sc;
        #pragma unroll
        for (int j = 0; j < 4; ++j) {
            short4v v;
            v[0] = ld[sc + j*4 + 0][d]; v[1] = ld[sc + j*4 + 1][d];
            v[2] = ld[sc + j*4 + 2][d]; v[3] = ld[sc + j*4 + 3][d];
            *(short4v*)(op + j * 4) = v;
        }
    }
}

// ---------------- fused attn: 2-phase LDS-staged QK^T -> exp -> {rowsum, Et, PV} + attn epilogue ----
// grid 1024 (XCD-swizzled). K/V double-buffered in LDS; epilogue re-reads own Et (L2-hot)
// and writes normalized f32 attn as fully-coalesced contiguous 512KB/block.
__global__ __launch_bounds__(256) void attnpv_kernel(
    const u16* __restrict__ Qh, const u16* __restrict__ Kh, const u16* __restrict__ Vt,
    const u64* __restrict__ bits,
    u16* __restrict__ Et, float* __restrict__ attn, u16* __restrict__ heads)
{
    const int j   = blockIdx.x;
    const int lid = (j & 7) * 128 + (j >> 3);     // XCD-contiguous bh ranges
    const int qt = lid & 31, bh = lid >> 5;
    const int b = bh >> 3, h = bh & 7;
    const int m0 = qt * 64;
    const int t = threadIdx.x, l = t & 63, w = t >> 6;
    const int q = l & 15, G = l >> 4;
    const int qrow = m0 + w*16 + q;
    __shared__ u16 kbuf[2][4096];          // 64x64 bf16 K tile, XOR-swizzled rows
    __shared__ u16 vbuf[2][4096];          // 64x64 bf16 V^T tile
    __shared__ u16 alds[4][1024];          // per-wave 16x64 E tile
    __shared__ float sinv[64];
    u16* my = alds[w];

    const size_t qbase = (((size_t)bh << 11) + qrow) * 64;
    bf16x8 qf0 = *(const bf16x8*)(Qh + qbase + G*8);
    bf16x8 qf1 = *(const bf16x8*)(Qh + qbase + 32 + G*8);
    const u64* brow = bits + (((size_t)b << 11) + qrow) * 32;
    const int swz = (q & 7) << 3;
    const int sr  = l >> 2;
    const int c16 = (l & 3) * 16;
    const int ssw = (sr & 7) << 3;
    u16* etq = Et + (((size_t)bh * 32 + qt) << 17);

    // staging geometry: thread covers rows srow0 (i=0) and srow0+32 (i=1), 16B each
    const int srow0 = t >> 3;
    const int scol  = (t & 7) * 8;
    const u16* Kbase = Kh + (((size_t)bh << 11) * 64);
    const u16* Vbase = Vt + (((size_t)bh << 6) * 2048);
    const int eswz = (t * 8) ^ ((srow0 & 7) << 3);   // swizzled dest element (i=0); i=1: +2048

    bf16x8 sk0, sk1, sv0, sv1;
    float rs = 0.f;
    f32x4 pacc[4] = {};

    // prologue: stage tile 0
    {
        const u16* kp = Kbase + (size_t)srow0 * 64 + scol;
        sk0 = *(const bf16x8*)kp;
        sk1 = *(const bf16x8*)(kp + 32 * 64);
        const u16* vp = Vbase + (size_t)srow0 * 2048 + scol;
        sv0 = *(const bf16x8*)vp;
        sv1 = *(const bf16x8*)(vp + 32 * 2048);
        *(bf16x8*)&kbuf[0][eswz]        = sk0;
        *(bf16x8*)&kbuf[0][2048 + eswz] = sk1;
        *(bf16x8*)&vbuf[0][eswz]        = sv0;
        *(bf16x8*)&vbuf[0][2048 + eswz] = sv1;
    }
    __syncthreads();

    for (int kt = 0; kt < 32; ++kt) {
        const int cur = kt & 1;
        if (kt < 31) {                      // issue next-tile loads early
            const int n1 = (kt + 1) * 64;
            const u16* kp = Kbase + (size_t)(n1 + srow0) * 64 + scol;
            sk0 = *(const bf16x8*)kp;
            sk1 = *(const bf16x8*)(kp + 32 * 64);
            const u16* vp = Vbase + (size_t)srow0 * 2048 + n1 + scol;
            sv0 = *(const bf16x8*)vp;
            sv1 = *(const bf16x8*)(vp + 32 * 2048);
        }
        // QK^T from LDS
        f32x4 acc[4] = {};
        #pragma unroll
        for (int mt = 0; mt < 4; ++mt) {
            const int r = mt*16 + q;
            const int rsw = (r & 7) << 3;
            bf16x8 k0 = *(const bf16x8*)&kbuf[cur][(r*64 +      G*8) ^ rsw];
            bf16x8 k1 = *(const bf16x8*)&kbuf[cur][(r*64 + 32 + G*8) ^ rsw];
            acc[mt] = MFMA16(k0, qf0, acc[mt], 0, 0, 0);
            acc[mt] = MFMA16(k1, qf1, acc[mt], 0, 0, 0);
        }
        const u64 mw = brow[kt];
        #pragma unroll
        for (int mt = 0; mt < 4; ++mt) {
            short4v sv;
            #pragma unroll
            for (int r = 0; r < 4; ++r) {
                const int c = mt*16 + G*4 + r;
                const float e = ((mw >> c) & 1) ? 0.f : exp2f(acc[mt][r] * L2E);
                rs += e;
                sv[r] = (short)f2bf(e);
            }
            *(short4v*)&my[(q*64 + mt*16 + G*4) ^ swz] = sv;
        }
        bf16x8 an0 = *(const bf16x8*)&my[(q*64 +  0 + G*8) ^ swz];
        bf16x8 an1 = *(const bf16x8*)&my[(q*64 + 32 + G*8) ^ swz];
        // E tile store: wave writes its 16x64 tile as contiguous 2KB
        {
            u16* et = etq + (kt << 12) + (w * 16) * 64;
            bf16x8 e0 = *(const bf16x8*)&my[sr*64 + ((c16 + 0) ^ ssw)];
            bf16x8 e1 = *(const bf16x8*)&my[sr*64 + ((c16 + 8) ^ ssw)];
            *(bf16x8*)(et + sr*64 + c16)     = e0;
            *(bf16x8*)(et + sr*64 + c16 + 8) = e1;
        }
        // PV from LDS
        #pragma unroll
        for (int dmt = 0; dmt < 4; ++dmt) {
            const int r = dmt*16 + q;
            const int rsw = (r & 7) << 3;
            bf16x8 v0 = *(const bf16x8*)&vbuf[cur][(r*64 +      G*8) ^ rsw];
            bf16x8 v1 = *(const bf16x8*)&vbuf[cur][(r*64 + 32 + G*8) ^ rsw];
            pacc[dmt] = MFMA16(v0, an0, pacc[dmt], 0, 0, 0);
            pacc[dmt] = MFMA16(v1, an1, pacc[dmt], 0, 0, 0);
        }
        // write staged tile kt+1 into the other buffer
        if (kt < 31) {
            const int nxt = cur ^ 1;
            *(bf16x8*)&kbuf[nxt][eswz]        = sk0;
            *(bf16x8*)&kbuf[nxt][2048 + eswz] = sk1;
            *(bf16x8*)&vbuf[nxt][eswz]        = sv0;
            *(bf16x8*)&vbuf[nxt][2048 + eswz] = sv1;
        }
        __syncthreads();
    }
    // row sums -> inv (reduce over the 4 G-groups holding the same q-row)
    rs += __shfl_xor(rs, 16);
    rs += __shfl_xor(rs, 32);
    const float inv = 1.0f / rs;
    if (G == 0) sinv[w*16 + q] = inv;
    #pragma unroll
    for (int dmt = 0; dmt < 4; ++dmt) {
        short4v sv;
        #pragma unroll
        for (int r = 0; r < 4; ++r) sv[r] = (short)f2bf(pacc[dmt][r] * inv);
        *(short4v*)&heads[(((size_t)b << 11) + qrow) * 512 + h*64 + dmt*16 + G*4] = sv;
    }
    __syncthreads();   // Et writes visible (barrier drains vmcnt), sinv ready

    // epilogue: attn[m0..m0+63][0..2047] = Et * sinv — contiguous 512KB block write.
    // wave w covers cols w*512..+511 (kt = w*8..w*8+7); lanes: kt = w*8+(l>>3), col (l&7)*8.
    {
        const int ktw = w*8 + (l >> 3);
        const int cc  = (l & 7) * 8;
        const u16* tb = etq + (ktw << 12) + cc;
        float* ab = attn + ((((size_t)bh << 11) + m0) << 11) + ktw*64 + cc;
        for (int r = 0; r < 64; ++r) {
            bf16x8 e = *(const bf16x8*)(tb + r*64);
            const float iv = sinv[r];
            f32x4 lo, hi;
            #pragma unroll
            for (int jj = 0; jj < 4; ++jj) {
                lo[jj] = bf2f((u16)e[jj])     * iv;
                hi[jj] = bf2f((u16)e[jj + 4]) * iv;
            }
            *(f32x4*)(ab + (size_t)r * 2048)     = lo;
            *(f32x4*)(ab + (size_t)r * 2048 + 4) = hi;
        }
    }
}

// ---------------- K4: out = heads(bf16) @ wo + q residual ----------------
__global__ __launch_bounds__(256) void outgemm_kernel(
    const u16* __restrict__ heads, const u16* __restrict__ wt,
    const float* __restrict__ qin, float* __restrict__ out)
{
    const int m0 = blockIdx.x * 64, n0b = blockIdx.y * 64;
    const int t = threadIdx.x, l = t & 63, w = t >> 6;
    const int q = l & 15, G = l >> 4;
    const int wr = w >> 1, wc = w & 1;
    const u16* W = wt + (size_t)3 * 512 * 512;
    f32x4 acc[2][2] = {};
    for (int k0 = 0; k0 < 512; k0 += 32) {
        bf16x8 af[2], bfr[2];
        #pragma unroll
        for (int mi = 0; mi < 2; ++mi)
            af[mi] = *(const bf16x8*)(heads + (size_t)(m0 + wr*32 + mi*16 + q) * 512 + k0 + G*8);
        #pragma unroll
        for (int tn = 0; tn < 2; ++tn)
            bfr[tn] = *(const bf16x8*)(W + (size_t)(n0b + wc*32 + tn*16 + q) * 512 + k0 + G*8);
        #pragma unroll
        for (int mi = 0; mi < 2; ++mi)
            #pragma unroll
            for (int tn = 0; tn < 2; ++tn)
                acc[mi][tn] = MFMA16(af[mi], bfr[tn], acc[mi][tn], 0, 0, 0);
    }
    #pragma unroll
    for (int mi = 0; mi < 2; ++mi)
        #pragma unroll
        for (int r = 0; r < 4; ++r) {
            const int m = m0 + wr*32 + mi*16 + G*4 + r;
            #pragma unroll
            for (int tn = 0; tn < 2; ++tn) {
                const int n = n0b + wc*32 + tn*16 + q;
                out[(size_t)m * 512 + n] = acc[mi][tn][r] + qin[(size_t)m * 512 + n];
            }
        }
}

// ---------------- K5: in-place row LayerNorm ----------------
__global__ __launch_bounds__(256) void ln_kernel(
    float* __restrict__ out, const float* __restrict__ g, const float* __restrict__ be)
{
    const int m = blockIdx.x;
    float* row = out + (size_t)m * 512;
    const int t = threadIdx.x;
    float2 v = ((const float2*)row)[t];
    float s  = block_sum256(v.x + v.y);
    float s2 = block_sum256(v.x * v.x + v.y * v.y);
    const float mu  = s * (1.0f / 512.0f);
    const float var = s2 * (1.0f / 512.0f) - mu * mu;
    const float inv = rsqrtf(var + LN_EPS);
    float2 gg = ((const float2*)g)[t];
    float2 bb = ((const float2*)be)[t];
    float2 r;
    r.x = (v.x - mu) * inv * gg.x + bb.x;
    r.y = (v.y - mu) * inv * gg.y + bb.y;
    ((float2*)row)[t] = r;
}

// ---------------- launch ----------------
extern "C" void kernel_launch(void* const* d_in, const int* in_sizes, int n_in,
                              void* d_out, int out_size, void* d_ws, size_t ws_size,
                              hipStream_t stream) {
    const float* q   = (const float*)d_in[0];
    const float* k   = (const float*)d_in[1];
    const float* v   = (const float*)d_in[2];
    const float* wq  = (const float*)d_in[3];
    const float* wk  = (const float*)d_in[4];
    const float* wv  = (const float*)d_in[5];
    const float* wo  = (const float*)d_in[6];
    const float* g   = (const float*)d_in[7];
    const float* be  = (const float*)d_in[8];
    const int*   msk = (const int*)d_in[9];

    float* out  = (float*)d_out;
    float* attn = out + (size_t)4 * 2048 * 512;

    const size_t nQKV = (size_t)32 * 2048 * 64;          // 4M u16 per tensor
    u16* Qh    = (u16*)d_ws;
    u16* Kh    = Qh + nQKV;
    u16* Vh    = Kh + nQKV;
    u16* Vt    = Vh + nQKV;
    u16* heads = Vt + nQKV;
    u16* wt    = heads + (size_t)8192 * 512;
    u64* bits  = (u64*)(wt + (size_t)4 * 512 * 512);
    u16* Et    = (u16*)(bits + (size_t)8192 * 32);       // 32*32*32*4096 bf16 = 268MB

    prepw_kernel  <<<dim3(8, 8, 4),    256, 0, stream>>>(wq, wk, wv, wo, wt);
    prepm_kernel  <<<dim3(2048),       256, 0, stream>>>(msk, bits);
    proj_kernel   <<<dim3(128, 8, 3),  256, 0, stream>>>(q, k, v, wt, Qh, Kh, Vh);
    vt_kernel     <<<dim3(32, 32),     256, 0, stream>>>(Vh, Vt);
    attnpv_kernel <<<dim3(1024),       256, 0, stream>>>(Qh, Kh, Vt, bits, Et, attn, heads);
    outgemm_kernel<<<dim3(128, 8),     256, 0, stream>>>(heads, wt, q, out);
    ln_kernel     <<<dim3(8192),       256, 0, stream>>>(out, g, be);
}

// Round 11
// 444.841 us; speedup vs baseline: 1.6690x; 1.1287x over previous
//
#include <hip/hip_runtime.h>
#include <cstddef>

typedef __attribute__((ext_vector_type(8))) short bf16x8;
typedef __attribute__((ext_vector_type(4))) float f32x4;
typedef __attribute__((ext_vector_type(2))) float f32x2;
typedef __attribute__((ext_vector_type(4))) short short4v;
typedef unsigned long long u64;
typedef unsigned int u32;
typedef unsigned short u16;

#define MFMA16 __builtin_amdgcn_mfma_f32_16x16x32_bf16
static constexpr float LN_EPS = 1e-5f;
static constexpr float L2E = 1.44269504f;

__device__ __forceinline__ u16 f2bf(float f) {
    u32 u = __builtin_bit_cast(u32, f);
    return (u16)((u + 0x7FFFu + ((u >> 16) & 1u)) >> 16);
}
__device__ __forceinline__ float bf2f(u16 h) {
    u32 u = ((u32)h) << 16;
    return __builtin_bit_cast(float, u);
}

// ---------------- block-wide sum (256 threads) ----------------
__device__ __forceinline__ float block_sum256(float v) {
    __shared__ float sc[4];
    #pragma unroll
    for (int o = 32; o > 0; o >>= 1) v += __shfl_down(v, o);
    if ((threadIdx.x & 63) == 0) sc[threadIdx.x >> 6] = v;
    __syncthreads();
    v = sc[0] + sc[1] + sc[2] + sc[3];
    __syncthreads();
    return v;
}

// ---------------- prep: weights fp32 [k][n] -> bf16 Wt [mat][n][k] ----------------
__global__ __launch_bounds__(256) void prepw_kernel(
    const float* __restrict__ wq, const float* __restrict__ wk,
    const float* __restrict__ wv, const float* __restrict__ wo,
    u16* __restrict__ wt)
{
    const int mat = blockIdx.z;
    const float* W = mat == 0 ? wq : mat == 1 ? wk : mat == 2 ? wv : wo;
    const int k0 = blockIdx.x * 64, n0 = blockIdx.y * 64;
    __shared__ u16 ld[64][72];
    const int t = threadIdx.x;
    {
        const int kk = t >> 2;
        #pragma unroll
        for (int j = 0; j < 4; ++j) {
            const int nn = ((t & 3) + j * 4) * 4;
            float4 x = *(const float4*)&W[(size_t)(k0 + kk) * 512 + n0 + nn];
            ld[kk][nn + 0] = f2bf(x.x); ld[kk][nn + 1] = f2bf(x.y);
            ld[kk][nn + 2] = f2bf(x.z); ld[kk][nn + 3] = f2bf(x.w);
        }
    }
    __syncthreads();
    {
        const int n = t & 63, kc = (t >> 6) * 16;
        u16* op = wt + ((size_t)mat * 512 + n0 + n) * 512 + k0 + kc;
        #pragma unroll
        for (int j = 0; j < 4; ++j) {
            short4v v;
            v[0] = ld[kc + j*4 + 0][n]; v[1] = ld[kc + j*4 + 1][n];
            v[2] = ld[kc + j*4 + 2][n]; v[3] = ld[kc + j*4 + 3][n];
            *(short4v*)(op + j * 4) = v;
        }
    }
}

// ---------------- prep: mask int32 -> bit-packed u64 [8192 rows][32 words] ----------------
__global__ __launch_bounds__(256) void prepm_kernel(
    const int* __restrict__ mask, u64* __restrict__ bits)
{
    const int t = threadIdx.x;
    const int row = blockIdx.x * 4 + (t >> 6);
    const int wl = t & 63;
    const int* mrow = mask + (size_t)row * 2048;
    u64* brow = bits + (size_t)row * 32;
    #pragma unroll 8
    for (int it = 0; it < 32; ++it) {
        u64 b = __ballot(mrow[it * 64 + wl] != 0);
        if (wl == 0) brow[it] = b;
    }
}

// ---------------- K1: projections via MFMA. X fp32 @ Wt -> Qh/Kh bf16 [bh][s][64], V -> Vt [bh][64][2048]
__global__ __launch_bounds__(256) void proj_kernel(
    const float* __restrict__ qin, const float* __restrict__ kin, const float* __restrict__ vin,
    const u16* __restrict__ wt,
    u16* __restrict__ Qh, u16* __restrict__ Kh, u16* __restrict__ Vt)
{
    const int z = blockIdx.z;
    const float* X = z == 0 ? qin : (z == 1 ? kin : vin);
    const u16* W = wt + (size_t)z * 512 * 512;
    const int m0 = blockIdx.x * 64;
    const int h = blockIdx.y;
    const int t = threadIdx.x, l = t & 63, w = t >> 6;
    const int q = l & 15, G = l >> 4;
    const int wr = w >> 1, wc = w & 1;

    f32x4 acc[2][2] = {};
    for (int k0 = 0; k0 < 512; k0 += 32) {
        bf16x8 af[2], bfr[2];
        #pragma unroll
        for (int mi = 0; mi < 2; ++mi) {
            const float* xp = X + (size_t)(m0 + wr*32 + mi*16 + q) * 512 + k0 + G*8;
            float4 x0 = *(const float4*)xp;
            float4 x1 = *(const float4*)(xp + 4);
            bf16x8 a;
            a[0] = f2bf(x0.x); a[1] = f2bf(x0.y); a[2] = f2bf(x0.z); a[3] = f2bf(x0.w);
            a[4] = f2bf(x1.x); a[5] = f2bf(x1.y); a[6] = f2bf(x1.z); a[7] = f2bf(x1.w);
            af[mi] = a;
        }
        #pragma unroll
        for (int tn = 0; tn < 2; ++tn)
            bfr[tn] = *(const bf16x8*)(W + (size_t)(h*64 + wc*32 + tn*16 + q) * 512 + k0 + G*8);
        #pragma unroll
        for (int mi = 0; mi < 2; ++mi)
            #pragma unroll
            for (int tn = 0; tn < 2; ++tn)
                acc[mi][tn] = MFMA16(af[mi], bfr[tn], acc[mi][tn], 0, 0, 0);
    }
    if (z == 2) {
        // V: write transposed directly -> Vt[bh][d][s], 4 consecutive s per lane (8B)
        #pragma unroll
        for (int mi = 0; mi < 2; ++mi)
            #pragma unroll
            for (int tn = 0; tn < 2; ++tn) {
                const int d = wc*32 + tn*16 + q;
                const int m = m0 + wr*32 + mi*16 + G*4;
                const int bb = m >> 11, s = m & 2047;
                short4v sv;
                #pragma unroll
                for (int r = 0; r < 4; ++r) sv[r] = (short)f2bf(acc[mi][tn][r]);
                *(short4v*)&Vt[(((size_t)(bb*8 + h) << 6) + d) * 2048 + s] = sv;
            }
    } else {
        u16* O = z == 0 ? Qh : Kh;
        const float scv = (z == 0) ? 0.125f : 1.0f;   // fold 1/sqrt(64) into Q (exact pow2)
        #pragma unroll
        for (int mi = 0; mi < 2; ++mi)
            #pragma unroll
            for (int tn = 0; tn < 2; ++tn)
                #pragma unroll
                for (int r = 0; r < 4; ++r) {
                    const int m = m0 + wr*32 + mi*16 + G*4 + r;
                    const int bb = m >> 11, s = m & 2047;
                    const int d = wc*32 + tn*16 + q;
                    O[(((size_t)(bb*8 + h) << 11) + s) * 64 + d] = f2bf(acc[mi][tn][r] * scv);
                }
    }
}

// ---------------- fused attn, two-phase: P1 rowsums (K LDS-staged); P2 recompute QK,
// write normalized f32 attn directly (in-loop 512B-burst flushes), PV. No Et buffer.
__global__ __launch_bounds__(256) void attnpv_kernel(
    const u16* __restrict__ Qh, const u16* __restrict__ Kh, const u16* __restrict__ Vt,
    const u64* __restrict__ bits,
    float* __restrict__ attn, u16* __restrict__ heads)
{
    const int j   = blockIdx.x;
    const int lid = (j & 7) * 128 + (j >> 3);     // XCD-contiguous bh ranges
    const int qt = lid & 31, bh = lid >> 5;
    const int b = bh >> 3, h = bh & 7;
    const int m0 = qt * 64;
    const int t = threadIdx.x, l = t & 63, w = t >> 6;
    const int q = l & 15, G = l >> 4;
    const int qrow = m0 + w*16 + q;
    __shared__ u16 kbuf[2][4096];          // 64x64 bf16 K tile, XOR-swizzled rows
    __shared__ u16 vbuf[2][4096];          // 64x64 bf16 V^T tile
    __shared__ u16 alds2[4][2048];         // per-wave 2x(16x64) E tiles
    __shared__ float sinv[64];
    u16* alds2w = alds2[w];

    const size_t qbase = (((size_t)bh << 11) + qrow) * 64;
    bf16x8 qf0 = *(const bf16x8*)(Qh + qbase + G*8);
    bf16x8 qf1 = *(const bf16x8*)(Qh + qbase + 32 + G*8);
    const u64* brow = bits + (((size_t)b << 11) + qrow) * 32;
    const int swz = (q & 7) << 3;

    // staging geometry: thread covers rows srow0 (i=0) and srow0+32 (i=1), 16B each
    const int srow0 = t >> 3;
    const int scol  = (t & 7) * 8;
    const u16* Kbase = Kh + (((size_t)bh << 11) * 64);
    const u16* Vbase = Vt + (((size_t)bh << 6) * 2048);
    const int eswz = (t * 8) ^ ((srow0 & 7) << 3);

    bf16x8 sk0, sk1, sv0, sv1;
    float rs = 0.f;

    // ======== phase 1: row sums (K only) ========
    {
        const u16* kp = Kbase + (size_t)srow0 * 64 + scol;
        sk0 = *(const bf16x8*)kp;
        sk1 = *(const bf16x8*)(kp + 32 * 64);
        *(bf16x8*)&kbuf[0][eswz]        = sk0;
        *(bf16x8*)&kbuf[0][2048 + eswz] = sk1;
    }
    __syncthreads();
    for (int kt = 0; kt < 32; ++kt) {
        const int cur = kt & 1;
        if (kt < 31) {
            const u16* kp = Kbase + (size_t)((kt + 1) * 64 + srow0) * 64 + scol;
            sk0 = *(const bf16x8*)kp;
            sk1 = *(const bf16x8*)(kp + 32 * 64);
        }
        f32x4 acc[4] = {};
        #pragma unroll
        for (int mt = 0; mt < 4; ++mt) {
            const int r = mt*16 + q;
            const int rsw = (r & 7) << 3;
            bf16x8 k0 = *(const bf16x8*)&kbuf[cur][(r*64 +      G*8) ^ rsw];
            bf16x8 k1 = *(const bf16x8*)&kbuf[cur][(r*64 + 32 + G*8) ^ rsw];
            acc[mt] = MFMA16(k0, qf0, acc[mt], 0, 0, 0);
            acc[mt] = MFMA16(k1, qf1, acc[mt], 0, 0, 0);
        }
        const u64 mw = brow[kt];
        #pragma unroll
        for (int mt = 0; mt < 4; ++mt)
            #pragma unroll
            for (int r = 0; r < 4; ++r) {
                const int c = mt*16 + G*4 + r;
                rs += ((mw >> c) & 1) ? 0.f : exp2f(acc[mt][r] * L2E);
            }
        if (kt < 31) {
            *(bf16x8*)&kbuf[cur ^ 1][eswz]        = sk0;
            *(bf16x8*)&kbuf[cur ^ 1][2048 + eswz] = sk1;
        }
        __syncthreads();
    }
    rs += __shfl_xor(rs, 16);
    rs += __shfl_xor(rs, 32);
    const float inv = 1.0f / rs;
    if (G == 0) sinv[w*16 + q] = inv;
    __syncthreads();

    // ======== phase 2: recompute QK, write normalized attn, PV ========
    f32x4 pacc[4] = {};
    {
        const u16* kp = Kbase + (size_t)srow0 * 64 + scol;
        sk0 = *(const bf16x8*)kp;
        sk1 = *(const bf16x8*)(kp + 32 * 64);
        const u16* vp = Vbase + (size_t)srow0 * 2048 + scol;
        sv0 = *(const bf16x8*)vp;
        sv1 = *(const bf16x8*)(vp + 32 * 2048);
        *(bf16x8*)&kbuf[0][eswz]        = sk0;
        *(bf16x8*)&kbuf[0][2048 + eswz] = sk1;
        *(bf16x8*)&vbuf[0][eswz]        = sv0;
        *(bf16x8*)&vbuf[0][2048 + eswz] = sv1;
    }
    __syncthreads();
    for (int kt = 0; kt < 32; ++kt) {
        const int cur = kt & 1;
        if (kt < 31) {
            const int n1 = (kt + 1) * 64;
            const u16* kp = Kbase + (size_t)(n1 + srow0) * 64 + scol;
            sk0 = *(const bf16x8*)kp;
            sk1 = *(const bf16x8*)(kp + 32 * 64);
            const u16* vp = Vbase + (size_t)srow0 * 2048 + n1 + scol;
            sv0 = *(const bf16x8*)vp;
            sv1 = *(const bf16x8*)(vp + 32 * 2048);
        }
        f32x4 acc[4] = {};
        #pragma unroll
        for (int mt = 0; mt < 4; ++mt) {
            const int r = mt*16 + q;
            const int rsw = (r & 7) << 3;
            bf16x8 k0 = *(const bf16x8*)&kbuf[cur][(r*64 +      G*8) ^ rsw];
            bf16x8 k1 = *(const bf16x8*)&kbuf[cur][(r*64 + 32 + G*8) ^ rsw];
            acc[mt] = MFMA16(k0, qf0, acc[mt], 0, 0, 0);
            acc[mt] = MFMA16(k1, qf1, acc[mt], 0, 0, 0);
        }
        const u64 mw = brow[kt];
        u16* A2 = alds2w + (kt & 1) * 1024;
        #pragma unroll
        for (int mt = 0; mt < 4; ++mt) {
            short4v sv;
            #pragma unroll
            for (int r = 0; r < 4; ++r) {
                const int c = mt*16 + G*4 + r;
                const float e = ((mw >> c) & 1) ? 0.f : exp2f(acc[mt][r] * L2E);
                sv[r] = (short)f2bf(e);
            }
            *(short4v*)&A2[(q*64 + mt*16 + G*4) ^ swz] = sv;
        }
        bf16x8 an0 = *(const bf16x8*)&A2[(q*64 +  0 + G*8) ^ swz];
        bf16x8 an1 = *(const bf16x8*)&A2[(q*64 + 32 + G*8) ^ swz];
        #pragma unroll
        for (int dmt = 0; dmt < 4; ++dmt) {
            const int r = dmt*16 + q;
            const int rsw = (r & 7) << 3;
            bf16x8 v0 = *(const bf16x8*)&vbuf[cur][(r*64 +      G*8) ^ rsw];
            bf16x8 v1 = *(const bf16x8*)&vbuf[cur][(r*64 + 32 + G*8) ^ rsw];
            pacc[dmt] = MFMA16(v0, an0, pacc[dmt], 0, 0, 0);
            pacc[dmt] = MFMA16(v1, an1, pacc[dmt], 0, 0, 0);
        }
        if (kt < 31) {
            const int nxt = cur ^ 1;
            *(bf16x8*)&kbuf[nxt][eswz]        = sk0;
            *(bf16x8*)&kbuf[nxt][2048 + eswz] = sk1;
            *(bf16x8*)&vbuf[nxt][eswz]        = sv0;
            *(bf16x8*)&vbuf[nxt][2048 + eswz] = sv1;
        }
        if (kt & 1) {
            // flush 2 staged kt tiles: per row, wave writes 512B contiguous (128 keys f32)
            const int ktg = kt >> 1;                 // 0..15
            const u16* A2f = alds2w + (l >> 5) * 1024;
            float* awbase = attn + ((((size_t)bh << 11) + m0 + w*16) << 11) + ktg*128 + l*2;
            #pragma unroll
            for (int r = 0; r < 16; ++r) {
                const float iv = sinv[w*16 + r];
                const u32 e2 = *(const u32*)&A2f[(r*64 + (l & 31)*2) ^ ((r & 7) << 3)];
                f32x2 o;
                o[0] = bf2f((u16)(e2 & 0xffffu)) * iv;
                o[1] = bf2f((u16)(e2 >> 16))     * iv;
                *(f32x2*)(awbase + (size_t)r * 2048) = o;
            }
        }
        __syncthreads();
    }
    #pragma unroll
    for (int dmt = 0; dmt < 4; ++dmt) {
        short4v sv;
        #pragma unroll
        for (int r = 0; r < 4; ++r) sv[r] = (short)f2bf(pacc[dmt][r] * inv);
        *(short4v*)&heads[(((size_t)b << 11) + qrow) * 512 + h*64 + dmt*16 + G*4] = sv;
    }
}

// ---------------- K4: out = heads(bf16) @ wo + q residual ----------------
__global__ __launch_bounds__(256) void outgemm_kernel(
    const u16* __restrict__ heads, const u16* __restrict__ wt,
    const float* __restrict__ qin, float* __restrict__ out)
{
    const int m0 = blockIdx.x * 64, n0b = blockIdx.y * 64;
    const int t = threadIdx.x, l = t & 63, w = t >> 6;
    const int q = l & 15, G = l >> 4;
    const int wr = w >> 1, wc = w & 1;
    const u16* W = wt + (size_t)3 * 512 * 512;
    f32x4 acc[2][2] = {};
    for (int k0 = 0; k0 < 512; k0 += 32) {
        bf16x8 af[2], bfr[2];
        #pragma unroll
        for (int mi = 0; mi < 2; ++mi)
            af[mi] = *(const bf16x8*)(heads + (size_t)(m0 + wr*32 + mi*16 + q) * 512 + k0 + G*8);
        #pragma unroll
        for (int tn = 0; tn < 2; ++tn)
            bfr[tn] = *(const bf16x8*)(W + (size_t)(n0b + wc*32 + tn*16 + q) * 512 + k0 + G*8);
        #pragma unroll
        for (int mi = 0; mi < 2; ++mi)
            #pragma unroll
            for (int tn = 0; tn < 2; ++tn)
                acc[mi][tn] = MFMA16(af[mi], bfr[tn], acc[mi][tn], 0, 0, 0);
    }
    #pragma unroll
    for (int mi = 0; mi < 2; ++mi)
        #pragma unroll
        for (int r = 0; r < 4; ++r) {
            const int m = m0 + wr*32 + mi*16 + G*4 + r;
            #pragma unroll
            for (int tn = 0; tn < 2; ++tn) {
                const int n = n0b + wc*32 + tn*16 + q;
                out[(size_t)m * 512 + n] = acc[mi][tn][r] + qin[(size_t)m * 512 + n];
            }
        }
}

// ---------------- K5: in-place row LayerNorm ----------------
__global__ __launch_bounds__(256) void ln_kernel(
    float* __restrict__ out, const float* __restrict__ g, const float* __restrict__ be)
{
    const int m = blockIdx.x;
    float* row = out + (size_t)m * 512;
    const int t = threadIdx.x;
    float2 v = ((const float2*)row)[t];
    float s  = block_sum256(v.x + v.y);
    float s2 = block_sum256(v.x * v.x + v.y * v.y);
    const float mu  = s * (1.0f / 512.0f);
    const float var = s2 * (1.0f / 512.0f) - mu * mu;
    const float inv = rsqrtf(var + LN_EPS);
    float2 gg = ((const float2*)g)[t];
    float2 bb = ((const float2*)be)[t];
    float2 r;
    r.x = (v.x - mu) * inv * gg.x + bb.x;
    r.y = (v.y - mu) * inv * gg.y + bb.y;
    ((float2*)row)[t] = r;
}

// ---------------- launch ----------------
extern "C" void kernel_launch(void* const* d_in, const int* in_sizes, int n_in,
                              void* d_out, int out_size, void* d_ws, size_t ws_size,
                              hipStream_t stream) {
    const float* q   = (const float*)d_in[0];
    const float* k   = (const float*)d_in[1];
    const float* v   = (const float*)d_in[2];
    const float* wq  = (const float*)d_in[3];
    const float* wk  = (const float*)d_in[4];
    const float* wv  = (const float*)d_in[5];
    const float* wo  = (const float*)d_in[6];
    const float* g   = (const float*)d_in[7];
    const float* be  = (const float*)d_in[8];
    const int*   msk = (const int*)d_in[9];

    float* out  = (float*)d_out;
    float* attn = out + (size_t)4 * 2048 * 512;

    const size_t nQKV = (size_t)32 * 2048 * 64;          // 4M u16 per tensor
    u16* Qh    = (u16*)d_ws;
    u16* Kh    = Qh + nQKV;
    u16* Vt    = Kh + nQKV;
    u16* heads = Vt + nQKV;
    u16* wt    = heads + (size_t)8192 * 512;
    u64* bits  = (u64*)(wt + (size_t)4 * 512 * 512);

    prepw_kernel  <<<dim3(8, 8, 4),    256, 0, stream>>>(wq, wk, wv, wo, wt);
    prepm_kernel  <<<dim3(2048),       256, 0, stream>>>(msk, bits);
    proj_kernel   <<<dim3(128, 8, 3),  256, 0, stream>>>(q, k, v, wt, Qh, Kh, Vt);
    attnpv_kernel <<<dim3(1024),       256, 0, stream>>>(Qh, Kh, Vt, bits, attn, heads);
    outgemm_kernel<<<dim3(128, 8),     256, 0, stream>>>(heads, wt, q, out);
    ln_kernel     <<<dim3(8192),       256, 0, stream>>>(out, g, be);
}